// Round 1
// baseline (6899.386 us; speedup 1.0000x reference)
//
#include <hip/hip_runtime.h>
#include <hip/hip_bf16.h>

#define TM 64
#define TN 64
#define TK 16

// ---------------- fp32 tiled GEMM: C[M,N] = A[M,K] @ B[K,N] + bias ----------------
__global__ __launch_bounds__(256) void gemm_bias_kernel(
    const float* __restrict__ A, const float* __restrict__ B,
    const float* __restrict__ bias, float* __restrict__ C,
    int M, int N, int K)
{
    __shared__ __align__(16) float As[TK][TM + 4];
    __shared__ __align__(16) float Bs[TK][TN];
    int tid = threadIdx.x;
    int row0 = blockIdx.x * TM;
    int col0 = blockIdx.y * TN;

    int tx = tid & 15;          // 0..15 -> col group
    int ty = tid >> 4;          // 0..15 -> row group
    int mr = ty * 4;
    int nc = tx * 4;

    float acc[4][4] = {};

    int la_row = tid >> 2;            // 0..63
    int la_col = (tid & 3) * 4;       // 0,4,8,12
    int lb_row = tid >> 4;            // 0..15
    int lb_col = (tid & 15) * 4;      // 0..60

    for (int k0 = 0; k0 < K; k0 += TK) {
        float4 av = make_float4(0.f, 0.f, 0.f, 0.f);
        int ar = row0 + la_row;
        if (ar < M) av = *(const float4*)(A + (size_t)ar * K + k0 + la_col);
        As[la_col + 0][la_row] = av.x;
        As[la_col + 1][la_row] = av.y;
        As[la_col + 2][la_row] = av.z;
        As[la_col + 3][la_row] = av.w;
        float4 bv = *(const float4*)(B + (size_t)(k0 + lb_row) * N + col0 + lb_col);
        *(float4*)&Bs[lb_row][lb_col] = bv;
        __syncthreads();
#pragma unroll
        for (int kk = 0; kk < TK; ++kk) {
            float4 a4 = *(const float4*)&As[kk][mr];
            float4 b4 = *(const float4*)&Bs[kk][nc];
            float ar_[4] = {a4.x, a4.y, a4.z, a4.w};
            float br_[4] = {b4.x, b4.y, b4.z, b4.w};
#pragma unroll
            for (int i = 0; i < 4; ++i)
#pragma unroll
                for (int j = 0; j < 4; ++j)
                    acc[i][j] += ar_[i] * br_[j];
        }
        __syncthreads();
    }

    float4 bb = *(const float4*)(bias + col0 + nc);
    float bbv[4] = {bb.x, bb.y, bb.z, bb.w};
#pragma unroll
    for (int i = 0; i < 4; ++i) {
        int r = row0 + mr + i;
        if (r < M) {
            float4 o;
            o.x = acc[i][0] + bbv[0];
            o.y = acc[i][1] + bbv[1];
            o.z = acc[i][2] + bbv[2];
            o.w = acc[i][3] + bbv[3];
            *(float4*)(C + (size_t)r * N + col0 + nc) = o;
        }
    }
}

// ---------------- degrees: D_v[N], cnt_e[M] ----------------
__global__ void degrees_kernel(const int* __restrict__ V, const int* __restrict__ E,
                               float* Dv, float* cnte, int nnz)
{
    int k = blockIdx.x * blockDim.x + threadIdx.x;
    if (k >= nnz) return;
    atomicAdd(&Dv[V[k]], 1.0f);
    atomicAdd(&cnte[E[k]], 1.0f);
}

// ---------------- score_node = X_feat @ a (wave per row) ----------------
__global__ void score_kernel(const float* __restrict__ Xf, const float* __restrict__ a,
                             float* __restrict__ score, int N)
{
    int row = blockIdx.x * (blockDim.x >> 6) + (threadIdx.x >> 6);
    int lane = threadIdx.x & 63;
    if (row >= N) return;
    float4 x = *(const float4*)(Xf + (size_t)row * 256 + lane * 4);
    float4 av = *(const float4*)(a + lane * 4);
    float p = x.x * av.x + x.y * av.y + x.z * av.z + x.w * av.w;
#pragma unroll
    for (int off = 32; off; off >>= 1) p += __shfl_down(p, off);
    if (lane == 0) score[row] = p;
}

// ordered-uint encoding for float atomicMax
__device__ __forceinline__ unsigned enc_f(float x) {
    unsigned b = __float_as_uint(x);
    return (b & 0x80000000u) ? ~b : (b | 0x80000000u);
}
__device__ __forceinline__ float dec_f(unsigned e) {
    unsigned b = (e & 0x80000000u) ? (e ^ 0x80000000u) : ~e;
    return __uint_as_float(b);
}

__global__ void edge_max_kernel(const float* __restrict__ score, const int* __restrict__ V,
                                const int* __restrict__ E, unsigned* menc, int nnz)
{
    int k = blockIdx.x * blockDim.x + threadIdx.x;
    if (k >= nnz) return;
    float s = score[V[k]];
    s = s >= 0.f ? s : 0.2f * s;            // leaky_relu(0.2)
    atomicMax(&menc[E[k]], enc_f(s));
}

__global__ void edge_expsum_kernel(const float* __restrict__ score, const int* __restrict__ V,
                                   const int* __restrict__ E, const unsigned* __restrict__ menc,
                                   float* denom, float* __restrict__ ex, int nnz)
{
    int k = blockIdx.x * blockDim.x + threadIdx.x;
    if (k >= nnz) return;
    float s = score[V[k]];
    s = s >= 0.f ? s : 0.2f * s;
    float m = dec_f(menc[E[k]]);
    float e = expf(s - m);
    ex[k] = e;
    atomicAdd(&denom[E[k]], e);
}

// ---------------- scatter: emsg[E[k], 0:256] += X_feat[V[k],:] * w  (stride 320) ----------------
__global__ void scatter_v2e_kernel(const float* __restrict__ Xf, const int* __restrict__ V,
                                   const int* __restrict__ E, const float* __restrict__ ex,
                                   const float* __restrict__ denom, float* emsg, int nnz)
{
    int k = blockIdx.x * 4 + (threadIdx.x >> 6);
    if (k >= nnz) return;
    int lane = threadIdx.x & 63;
    int v = V[k], e = E[k];
    float w = ex[k] / denom[e];
    float4 x = *(const float4*)(Xf + (size_t)v * 256 + lane * 4);
    float* d = emsg + (size_t)e * 320 + lane * 4;
    atomicAdd(d + 0, x.x * w);
    atomicAdd(d + 1, x.y * w);
    atomicAdd(d + 2, x.z * w);
    atomicAdd(d + 3, x.w * w);
}

// emsg: cols 0..255 -> elu in place; cols 256..319 -> copy S
__global__ void emsg_finish_kernel(float* emsg, const float* __restrict__ S, int M)
{
    int i = blockIdx.x * blockDim.x + threadIdx.x;
    if (i >= M * 320) return;
    int e = i / 320, c = i - e * 320;
    if (c < 256) {
        float v = emsg[i];
        emsg[i] = v > 0.f ? v : expm1f(v);
    } else {
        emsg[i] = S[(size_t)e * 64 + (c - 256)];
    }
}

// acc[V[k],:] += Y[E[k],:]   (both stride 256)
__global__ void scatter_e2v_kernel(const float* __restrict__ Y, const int* __restrict__ V,
                                   const int* __restrict__ E, float* acc, int nnz)
{
    int k = blockIdx.x * 4 + (threadIdx.x >> 6);
    if (k >= nnz) return;
    int lane = threadIdx.x & 63;
    int v = V[k], e = E[k];
    float4 y = *(const float4*)(Y + (size_t)e * 256 + lane * 4);
    float* d = acc + (size_t)v * 256 + lane * 4;
    atomicAdd(d + 0, y.x);
    atomicAdd(d + 1, y.y);
    atomicAdd(d + 2, y.z);
    atomicAdd(d + 3, y.w);
}

// hout = elu(seg_mean) + X_init
__global__ void layer_finish_kernel(const float* __restrict__ acc, const float* __restrict__ Xinit,
                                    const float* __restrict__ Dv, float* __restrict__ hout, int N)
{
    int i = blockIdx.x * blockDim.x + threadIdx.x;
    if (i >= N * 256) return;
    int r = i >> 8;
    float cnt = Dv[r];
    float m = cnt > 0.f ? acc[i] / cnt : 0.f;
    float e = m > 0.f ? m : expm1f(m);
    hout[i] = e + Xinit[i];
}

// ---------------- hyperconv helpers ----------------
__global__ void de_kernel(const int* __restrict__ V, const int* __restrict__ E,
                          const float* __restrict__ Dv, float* Deacc, int nnz)
{
    int k = blockIdx.x * blockDim.x + threadIdx.x;
    if (k >= nnz) return;
    atomicAdd(&Deacc[E[k]], Dv[V[k]]);
}

__global__ void de_finish_kernel(const float* __restrict__ Deacc, const float* __restrict__ cnte,
                                 float* __restrict__ Deinv, int M)
{
    int e = blockIdx.x * blockDim.x + threadIdx.x;
    if (e >= M) return;
    float De = Deacc[e] / (cnte[e] + 1.0f);
    Deinv[e] = De > 0.f ? rsqrtf(De) : 1.0f;
}

// dst[dIdx[k],:] += src[sIdx[k],:]  (stride 128, float2 per lane)
__global__ void scatter128_kernel(const float* __restrict__ src, const int* __restrict__ sIdx,
                                  float* dst, const int* __restrict__ dIdx, int nnz)
{
    int k = blockIdx.x * 4 + (threadIdx.x >> 6);
    if (k >= nnz) return;
    int lane = threadIdx.x & 63;
    int si = sIdx[k], di = dIdx[k];
    float2 x = *(const float2*)(src + (size_t)si * 128 + lane * 2);
    float* d = dst + (size_t)di * 128 + lane * 2;
    atomicAdd(d + 0, x.x);
    atomicAdd(d + 1, x.y);
}

// Yh = De_inv * (seg_mean)
__global__ void scale_yh_kernel(float* Yh, const float* __restrict__ cnte,
                                const float* __restrict__ Deinv, int M)
{
    int i = blockIdx.x * blockDim.x + threadIdx.x;
    if (i >= M * 128) return;
    int e = i >> 7;
    float cnt = cnte[e];
    float v = cnt > 0.f ? Yh[i] / cnt : 0.f;
    Yh[i] = Deinv[e] * v;
}

__global__ void final_kernel(const float* __restrict__ Xo, const float* __restrict__ Dv,
                             float* __restrict__ out, int N)
{
    int i = blockIdx.x * blockDim.x + threadIdx.x;
    if (i >= N * 128) return;
    int r = i >> 7;
    float dv = Dv[r];
    out[i] = dv > 0.f ? rsqrtf(dv) * Xo[i] : 0.f;
}

// ---------------- host-side layer driver ----------------
static void run_layer(const float* Xin, int K,
                      const float* Wx, const float* bx,
                      const float* Wv, const float* bv, const float* a,
                      const float* Wt, const float* bt, const float* S,
                      float* Xinit, float* Xfeat /* also acc */, float* emsg, float* Ybuf,
                      float* exbuf, float* score, unsigned* menc, float* denom,
                      const float* Dv, const int* V, const int* E,
                      float* hout, int N, int M, int NNZ, hipStream_t stream)
{
    dim3 gA((N + TM - 1) / TM, 256 / TN);
    gemm_bias_kernel<<<gA, 256, 0, stream>>>(Xin, Wx, bx, Xinit, N, 256, K);
    gemm_bias_kernel<<<gA, 256, 0, stream>>>(Xin, Wv, bv, Xfeat, N, 256, K);
    score_kernel<<<(N + 3) / 4, 256, 0, stream>>>(Xfeat, a, score, N);
    hipMemsetAsync(menc, 0, (size_t)M * 4, stream);
    hipMemsetAsync(denom, 0, (size_t)M * 4, stream);
    edge_max_kernel<<<(NNZ + 255) / 256, 256, 0, stream>>>(score, V, E, menc, NNZ);
    edge_expsum_kernel<<<(NNZ + 255) / 256, 256, 0, stream>>>(score, V, E, menc, denom, exbuf, NNZ);
    hipMemsetAsync(emsg, 0, (size_t)M * 320 * 4, stream);
    scatter_v2e_kernel<<<(NNZ + 3) / 4, 256, 0, stream>>>(Xfeat, V, E, exbuf, denom, emsg, NNZ);
    emsg_finish_kernel<<<((size_t)M * 320 + 255) / 256, 256, 0, stream>>>(emsg, S, M);
    dim3 gY((M + TM - 1) / TM, 256 / TN);
    gemm_bias_kernel<<<gY, 256, 0, stream>>>(emsg, Wt, bt, Ybuf, M, 256, 320);
    hipMemsetAsync(Xfeat, 0, (size_t)N * 256 * 4, stream);   // Xfeat now dead -> reuse as acc
    scatter_e2v_kernel<<<(NNZ + 3) / 4, 256, 0, stream>>>(Ybuf, V, E, Xfeat, NNZ);
    layer_finish_kernel<<<((size_t)N * 256 + 255) / 256, 256, 0, stream>>>(Xfeat, Xinit, Dv, hout, N);
}

extern "C" void kernel_launch(void* const* d_in, const int* in_sizes, int n_in,
                              void* d_out, int out_size, void* d_ws, size_t ws_size,
                              hipStream_t stream)
{
    const float* X   = (const float*)d_in[0];
    const int*   V   = (const int*)d_in[1];
    const int*   E   = (const int*)d_in[2];
    const float* S   = (const float*)d_in[3];
    const float* Wx0 = (const float*)d_in[4];  const float* bx0 = (const float*)d_in[5];
    const float* Wv0 = (const float*)d_in[6];  const float* bv0 = (const float*)d_in[7];
    const float* a0  = (const float*)d_in[8];
    const float* Wt0 = (const float*)d_in[9];  const float* bt0 = (const float*)d_in[10];
    const float* Wx1 = (const float*)d_in[11]; const float* bx1 = (const float*)d_in[12];
    const float* Wv1 = (const float*)d_in[13]; const float* bv1 = (const float*)d_in[14];
    const float* a1  = (const float*)d_in[15];
    const float* Wt1 = (const float*)d_in[16]; const float* bt1 = (const float*)d_in[17];
    const float* Wf  = (const float*)d_in[18]; const float* bf  = (const float*)d_in[19];

    int N   = in_sizes[0] / 128;
    int NNZ = in_sizes[1];
    int M   = in_sizes[3] / 64;

    float* ws = (float*)d_ws;
    size_t off = 0;
    float* h1    = ws + off; off += (size_t)N * 256;   // layer out (both layers; h2 aliases h1)
    float* Xinit = ws + off; off += (size_t)N * 256;   // also Xc (hyperconv)
    float* Xfeat = ws + off; off += (size_t)N * 256;   // also acc, also Xo (hyperconv)
    float* emsg  = ws + off; off += (size_t)M * 320;
    float* Ybuf  = ws + off; off += (size_t)M * 256;   // also Yh (hyperconv)
    float* exbuf = ws + off; off += (size_t)NNZ;
    float* score = ws + off; off += (size_t)N;
    unsigned* menc = (unsigned*)(ws + off); off += (size_t)M;
    float* denom = ws + off; off += (size_t)M;
    float* Dv    = ws + off; off += (size_t)N;
    float* cnte  = ws + off; off += (size_t)M;
    float* Deacc = ws + off; off += (size_t)M;
    float* Deinv = ws + off; off += (size_t)M;

    // degrees (V, E are constant across the whole net)
    hipMemsetAsync(Dv, 0, (size_t)N * 4, stream);
    hipMemsetAsync(cnte, 0, (size_t)M * 4, stream);
    degrees_kernel<<<(NNZ + 255) / 256, 256, 0, stream>>>(V, E, Dv, cnte, NNZ);

    // layer 0: input X (K=128), output h1
    run_layer(X, 128, Wx0, bx0, Wv0, bv0, a0, Wt0, bt0, S,
              Xinit, Xfeat, emsg, Ybuf, exbuf, score, menc, denom,
              Dv, V, E, h1, N, M, NNZ, stream);
    // layer 1: input h1 (K=256), output h1 (in-place safe: finish reads acc/Xinit only)
    run_layer(h1, 256, Wx1, bx1, Wv1, bv1, a1, Wt1, bt1, S,
              Xinit, Xfeat, emsg, Ybuf, exbuf, score, menc, denom,
              Dv, V, E, h1, N, M, NNZ, stream);

    // hyperconv
    float* Xc = Xinit;
    float* Yh = Ybuf;
    float* Xo = Xfeat;
    dim3 gC((N + TM - 1) / TM, 128 / TN);
    gemm_bias_kernel<<<gC, 256, 0, stream>>>(h1, Wf, bf, Xc, N, 128, 256);
    hipMemsetAsync(Yh, 0, (size_t)M * 128 * 4, stream);
    hipMemsetAsync(Deacc, 0, (size_t)M * 4, stream);
    de_kernel<<<(NNZ + 255) / 256, 256, 0, stream>>>(V, E, Dv, Deacc, NNZ);
    scatter128_kernel<<<(NNZ + 3) / 4, 256, 0, stream>>>(Xc, V, Yh, E, NNZ);   // Yh[E[k]] += Xc[V[k]]
    de_finish_kernel<<<(M + 255) / 256, 256, 0, stream>>>(Deacc, cnte, Deinv, M);
    scale_yh_kernel<<<((size_t)M * 128 + 255) / 256, 256, 0, stream>>>(Yh, cnte, Deinv, M);
    hipMemsetAsync(Xo, 0, (size_t)N * 128 * 4, stream);
    scatter128_kernel<<<(NNZ + 3) / 4, 256, 0, stream>>>(Yh, E, Xo, V, NNZ);   // Xo[V[k]] += Yh[E[k]]
    final_kernel<<<((size_t)N * 128 + 255) / 256, 256, 0, stream>>>(Xo, Dv, (float*)d_out, N);
}

// Round 2
// 1161.523 us; speedup vs baseline: 5.9399x; 5.9399x over previous
//
#include <hip/hip_runtime.h>
#include <hip/hip_bf16.h>

#define TM 64
#define TN 64
#define TK 16

// ---------------- fp32 tiled GEMM: C = A@B (+bias | +C) ----------------
__global__ __launch_bounds__(256) void gemm_bias_kernel(
    const float* __restrict__ A, const float* __restrict__ B,
    const float* __restrict__ bias, float* __restrict__ C,
    int M, int N, int K, int accum)
{
    __shared__ __align__(16) float As[TK][TM + 4];
    __shared__ __align__(16) float Bs[TK][TN];
    int tid = threadIdx.x;
    int row0 = blockIdx.x * TM;
    int col0 = blockIdx.y * TN;

    int tx = tid & 15;
    int ty = tid >> 4;
    int mr = ty * 4;
    int nc = tx * 4;

    float acc[4][4] = {};

    int la_row = tid >> 2;
    int la_col = (tid & 3) * 4;
    int lb_row = tid >> 4;
    int lb_col = (tid & 15) * 4;

    for (int k0 = 0; k0 < K; k0 += TK) {
        float4 av = make_float4(0.f, 0.f, 0.f, 0.f);
        int ar = row0 + la_row;
        if (ar < M) av = *(const float4*)(A + (size_t)ar * K + k0 + la_col);
        As[la_col + 0][la_row] = av.x;
        As[la_col + 1][la_row] = av.y;
        As[la_col + 2][la_row] = av.z;
        As[la_col + 3][la_row] = av.w;
        float4 bv = *(const float4*)(B + (size_t)(k0 + lb_row) * N + col0 + lb_col);
        *(float4*)&Bs[lb_row][lb_col] = bv;
        __syncthreads();
#pragma unroll
        for (int kk = 0; kk < TK; ++kk) {
            float4 a4 = *(const float4*)&As[kk][mr];
            float4 b4 = *(const float4*)&Bs[kk][nc];
            float ar_[4] = {a4.x, a4.y, a4.z, a4.w};
            float br_[4] = {b4.x, b4.y, b4.z, b4.w};
#pragma unroll
            for (int i = 0; i < 4; ++i)
#pragma unroll
                for (int j = 0; j < 4; ++j)
                    acc[i][j] += ar_[i] * br_[j];
        }
        __syncthreads();
    }

#pragma unroll
    for (int i = 0; i < 4; ++i) {
        int r = row0 + mr + i;
        if (r < M) {
            float* cp = C + (size_t)r * N + col0 + nc;
            float4 o;
            if (accum) {
                float4 c0 = *(const float4*)cp;
                o.x = acc[i][0] + c0.x; o.y = acc[i][1] + c0.y;
                o.z = acc[i][2] + c0.z; o.w = acc[i][3] + c0.w;
            } else {
                float4 bb = *(const float4*)(bias + col0 + nc);
                o.x = acc[i][0] + bb.x; o.y = acc[i][1] + bb.y;
                o.z = acc[i][2] + bb.z; o.w = acc[i][3] + bb.w;
            }
            *(float4*)cp = o;
        }
    }
}

// ---------------- CSR build ----------------
__global__ void count_kernel(const int* __restrict__ V, const int* __restrict__ E,
                             int* ecnt, int* ncnt, int nnz)
{
    int k = blockIdx.x * blockDim.x + threadIdx.x;
    if (k >= nnz) return;
    atomicAdd(&ecnt[E[k]], 1);
    atomicAdd(&ncnt[V[k]], 1);
}

__global__ __launch_bounds__(1024) void scan_kernel(const int* __restrict__ cnt,
                                                    int* __restrict__ off, int n)
{
    __shared__ int part[1024];
    int t = threadIdx.x;
    int chunk = (n + 1023) / 1024;
    int s0 = t * chunk;
    int s1 = min(n, s0 + chunk);
    int sum = 0;
    for (int i = s0; i < s1; ++i) sum += cnt[i];
    part[t] = sum;
    __syncthreads();
    for (int o = 1; o < 1024; o <<= 1) {
        int v = (t >= o) ? part[t - o] : 0;
        __syncthreads();
        part[t] += v;
        __syncthreads();
    }
    int base = (t > 0) ? part[t - 1] : 0;
    if (t == 0) off[0] = 0;
    for (int i = s0; i < s1; ++i) { base += cnt[i]; off[i + 1] = base; }
}

__global__ void fill_kernel(const int* __restrict__ V, const int* __restrict__ E,
                            int* ecur, int* ncur, int* edge_v, int* node_e, int nnz)
{
    int k = blockIdx.x * blockDim.x + threadIdx.x;
    if (k >= nnz) return;
    int v = V[k], e = E[k];
    int j = atomicAdd(&ecur[e], 1);
    edge_v[j] = v;
    int i = atomicAdd(&ncur[v], 1);
    node_e[i] = e;
}

// ---------------- score = X_feat @ a (wave per row) ----------------
__global__ void score_kernel(const float* __restrict__ Xf, const float* __restrict__ a,
                             float* __restrict__ score, int N)
{
    int row = blockIdx.x * (blockDim.x >> 6) + (threadIdx.x >> 6);
    int lane = threadIdx.x & 63;
    if (row >= N) return;
    float4 x = *(const float4*)(Xf + (size_t)row * 256 + lane * 4);
    float4 av = *(const float4*)(a + lane * 4);
    float p = x.x * av.x + x.y * av.y + x.z * av.z + x.w * av.w;
#pragma unroll
    for (int off = 32; off; off >>= 1) p += __shfl_down(p, off);
    if (lane == 0) score[row] = p;
}

// ---------------- per-edge softmax over CSR (wave per edge) ----------------
__global__ void edge_softmax_kernel(const float* __restrict__ score,
                                    const int* __restrict__ eoff,
                                    const int* __restrict__ edge_v,
                                    float* __restrict__ w, int M)
{
    int e = blockIdx.x * 4 + (threadIdx.x >> 6);
    if (e >= M) return;
    int lane = threadIdx.x & 63;
    int j0 = eoff[e], j1 = eoff[e + 1];
    if (j0 == j1) return;
    float m = -INFINITY;
    for (int j = j0 + lane; j < j1; j += 64) {
        float s = score[edge_v[j]];
        s = s >= 0.f ? s : 0.2f * s;
        m = fmaxf(m, s);
    }
#pragma unroll
    for (int o = 32; o; o >>= 1) m = fmaxf(m, __shfl_xor(m, o));
    float sum = 0.f;
    for (int j = j0 + lane; j < j1; j += 64) {
        float s = score[edge_v[j]];
        s = s >= 0.f ? s : 0.2f * s;
        sum += expf(s - m);
    }
#pragma unroll
    for (int o = 32; o; o >>= 1) sum += __shfl_xor(sum, o);
    float inv = 1.0f / sum;
    for (int j = j0 + lane; j < j1; j += 64) {
        float s = score[edge_v[j]];
        s = s >= 0.f ? s : 0.2f * s;
        w[j] = expf(s - m) * inv;
    }
}

// ---------------- Yv2e[e,:] = elu( sum_j Xf[edge_v[j],:] * w[j] )  (wave/edge) ----------------
__global__ void v2e_gather_kernel(const float* __restrict__ Xf,
                                  const int* __restrict__ eoff,
                                  const int* __restrict__ edge_v,
                                  const float* __restrict__ w,
                                  float* __restrict__ Yv, int M)
{
    int e = blockIdx.x * 4 + (threadIdx.x >> 6);
    if (e >= M) return;
    int lane = threadIdx.x & 63;
    int j0 = eoff[e], j1 = eoff[e + 1];
    float4 acc = make_float4(0.f, 0.f, 0.f, 0.f);
    for (int j = j0; j < j1; ++j) {
        int v = edge_v[j];
        float ww = w[j];
        float4 x = *(const float4*)(Xf + (size_t)v * 256 + lane * 4);
        acc.x += x.x * ww; acc.y += x.y * ww;
        acc.z += x.z * ww; acc.w += x.w * ww;
    }
    acc.x = acc.x > 0.f ? acc.x : expm1f(acc.x);
    acc.y = acc.y > 0.f ? acc.y : expm1f(acc.y);
    acc.z = acc.z > 0.f ? acc.z : expm1f(acc.z);
    acc.w = acc.w > 0.f ? acc.w : expm1f(acc.w);
    *(float4*)(Yv + (size_t)e * 256 + lane * 4) = acc;
}

// ---------------- h[v,:] = elu(mean_i Y[node_e[i],:]) + Xinit[v,:]  (wave/node) ----------------
__global__ void e2v_finish_kernel(const float* __restrict__ Y,
                                  const int* __restrict__ noff,
                                  const int* __restrict__ node_e,
                                  const float* __restrict__ Xinit,
                                  float* __restrict__ hout, int N)
{
    int v = blockIdx.x * 4 + (threadIdx.x >> 6);
    if (v >= N) return;
    int lane = threadIdx.x & 63;
    int i0 = noff[v], i1 = noff[v + 1];
    float4 acc = make_float4(0.f, 0.f, 0.f, 0.f);
    for (int i = i0; i < i1; ++i) {
        int e = node_e[i];
        float4 y = *(const float4*)(Y + (size_t)e * 256 + lane * 4);
        acc.x += y.x; acc.y += y.y; acc.z += y.z; acc.w += y.w;
    }
    float inv = (i1 > i0) ? 1.0f / (float)(i1 - i0) : 0.f;
    size_t base = (size_t)v * 256 + lane * 4;
    float4 xi = *(const float4*)(Xinit + base);
    float4 o;
    float m;
    m = acc.x * inv; o.x = (m > 0.f ? m : expm1f(m)) + xi.x;
    m = acc.y * inv; o.y = (m > 0.f ? m : expm1f(m)) + xi.y;
    m = acc.z * inv; o.z = (m > 0.f ? m : expm1f(m)) + xi.z;
    m = acc.w * inv; o.w = (m > 0.f ? m : expm1f(m)) + xi.w;
    *(float4*)(hout + base) = o;
}

// ---------------- hyperconv ----------------
__global__ void deinv_kernel(const int* __restrict__ eoff, const int* __restrict__ edge_v,
                             const int* __restrict__ noff, float* __restrict__ Deinv, int M)
{
    int e = blockIdx.x * blockDim.x + threadIdx.x;
    if (e >= M) return;
    int j0 = eoff[e], j1 = eoff[e + 1];
    float s = 0.f;
    for (int j = j0; j < j1; ++j) {
        int v = edge_v[j];
        s += (float)(noff[v + 1] - noff[v]);
    }
    float De = s / ((float)(j1 - j0) + 1.0f);
    Deinv[e] = De > 0.f ? rsqrtf(De) : 1.0f;
}

// Yh[e,:] = Deinv[e] * mean_j Xc[edge_v[j],:]   (stride 128, wave/edge, float2/lane)
__global__ void yh_kernel(const float* __restrict__ Xc,
                          const int* __restrict__ eoff, const int* __restrict__ edge_v,
                          const float* __restrict__ Deinv, float* __restrict__ Yh, int M)
{
    int e = blockIdx.x * 4 + (threadIdx.x >> 6);
    if (e >= M) return;
    int lane = threadIdx.x & 63;
    int j0 = eoff[e], j1 = eoff[e + 1];
    float2 acc = make_float2(0.f, 0.f);
    for (int j = j0; j < j1; ++j) {
        int v = edge_v[j];
        float2 x = *(const float2*)(Xc + (size_t)v * 128 + lane * 2);
        acc.x += x.x; acc.y += x.y;
    }
    float sc = ((j1 > j0) ? 1.0f / (float)(j1 - j0) : 0.f) * Deinv[e];
    float* d = Yh + (size_t)e * 128 + lane * 2;
    d[0] = acc.x * sc;
    d[1] = acc.y * sc;
}

// out[v,:] = Dv^-0.5 * sum_i Yh[node_e[i],:]
__global__ void xo_final_kernel(const float* __restrict__ Yh,
                                const int* __restrict__ noff, const int* __restrict__ node_e,
                                float* __restrict__ out, int N)
{
    int v = blockIdx.x * 4 + (threadIdx.x >> 6);
    if (v >= N) return;
    int lane = threadIdx.x & 63;
    int i0 = noff[v], i1 = noff[v + 1];
    float2 acc = make_float2(0.f, 0.f);
    for (int i = i0; i < i1; ++i) {
        int e = node_e[i];
        float2 y = *(const float2*)(Yh + (size_t)e * 128 + lane * 2);
        acc.x += y.x; acc.y += y.y;
    }
    float sc = (i1 > i0) ? rsqrtf((float)(i1 - i0)) : 0.f;
    float* d = out + (size_t)v * 128 + lane * 2;
    d[0] = acc.x * sc;
    d[1] = acc.y * sc;
}

// ---------------- host-side layer driver ----------------
static void run_layer(const float* Xin, int K,
                      const float* Wx, const float* bx,
                      const float* Wv, const float* bv, const float* a,
                      const float* Wt, const float* bt, const float* S,
                      float* Xinit, float* Xfeat, float* Yv2e, float* Ybuf,
                      float* wbuf, float* score,
                      const int* eoff, const int* edge_v,
                      const int* noff, const int* node_e,
                      float* hout, int N, int M, int NNZ, hipStream_t stream)
{
    dim3 gA((N + TM - 1) / TM, 256 / TN);
    gemm_bias_kernel<<<gA, 256, 0, stream>>>(Xin, Wx, bx, Xinit, N, 256, K, 0);
    gemm_bias_kernel<<<gA, 256, 0, stream>>>(Xin, Wv, bv, Xfeat, N, 256, K, 0);
    score_kernel<<<(N + 3) / 4, 256, 0, stream>>>(Xfeat, a, score, N);
    edge_softmax_kernel<<<(M + 3) / 4, 256, 0, stream>>>(score, eoff, edge_v, wbuf, M);
    v2e_gather_kernel<<<(M + 3) / 4, 256, 0, stream>>>(Xfeat, eoff, edge_v, wbuf, Yv2e, M);
    dim3 gY((M + TM - 1) / TM, 256 / TN);
    // Y = Yv2e @ Wt[0:256,:] + bt  ;  Y += S @ Wt[256:320,:]
    gemm_bias_kernel<<<gY, 256, 0, stream>>>(Yv2e, Wt, bt, Ybuf, M, 256, 256, 0);
    gemm_bias_kernel<<<gY, 256, 0, stream>>>(S, Wt + (size_t)256 * 256, nullptr, Ybuf, M, 256, 64, 1);
    e2v_finish_kernel<<<(N + 3) / 4, 256, 0, stream>>>(Ybuf, noff, node_e, Xinit, hout, N);
}

extern "C" void kernel_launch(void* const* d_in, const int* in_sizes, int n_in,
                              void* d_out, int out_size, void* d_ws, size_t ws_size,
                              hipStream_t stream)
{
    const float* X   = (const float*)d_in[0];
    const int*   V   = (const int*)d_in[1];
    const int*   E   = (const int*)d_in[2];
    const float* S   = (const float*)d_in[3];
    const float* Wx0 = (const float*)d_in[4];  const float* bx0 = (const float*)d_in[5];
    const float* Wv0 = (const float*)d_in[6];  const float* bv0 = (const float*)d_in[7];
    const float* a0  = (const float*)d_in[8];
    const float* Wt0 = (const float*)d_in[9];  const float* bt0 = (const float*)d_in[10];
    const float* Wx1 = (const float*)d_in[11]; const float* bx1 = (const float*)d_in[12];
    const float* Wv1 = (const float*)d_in[13]; const float* bv1 = (const float*)d_in[14];
    const float* a1  = (const float*)d_in[15];
    const float* Wt1 = (const float*)d_in[16]; const float* bt1 = (const float*)d_in[17];
    const float* Wf  = (const float*)d_in[18]; const float* bf  = (const float*)d_in[19];

    int N   = in_sizes[0] / 128;
    int NNZ = in_sizes[1];
    int M   = in_sizes[3] / 64;

    float* ws = (float*)d_ws;
    size_t off = 0;
    float* h1    = ws + off; off += (size_t)N * 256;
    float* Xinit = ws + off; off += (size_t)N * 256;   // also Xc (hyperconv reuse: no, Xc uses Xfeat)
    float* Xfeat = ws + off; off += (size_t)N * 256;   // also Xc (hyperconv, stride 128)
    float* Yv2e  = ws + off; off += (size_t)M * 256;
    float* Ybuf  = ws + off; off += (size_t)M * 256;   // also Yh (hyperconv, stride 128)
    float* wbuf  = ws + off; off += (size_t)NNZ;
    float* score = ws + off; off += (size_t)N;
    float* Deinv = ws + off; off += (size_t)M;
    int* eoff   = (int*)(ws + off); off += (size_t)(M + 1);
    int* ecur   = (int*)(ws + off); off += (size_t)M;
    int* edge_v = (int*)(ws + off); off += (size_t)NNZ;
    int* noff   = (int*)(ws + off); off += (size_t)(N + 1);
    int* ncur   = (int*)(ws + off); off += (size_t)N;
    int* node_e = (int*)(ws + off); off += (size_t)NNZ;

    // ---- build CSR (edge-sorted and node-sorted incidence) ----
    hipMemsetAsync(ecur, 0, (size_t)M * 4, stream);
    hipMemsetAsync(ncur, 0, (size_t)N * 4, stream);
    count_kernel<<<(NNZ + 255) / 256, 256, 0, stream>>>(V, E, ecur, ncur, NNZ);
    scan_kernel<<<1, 1024, 0, stream>>>(ecur, eoff, M);
    scan_kernel<<<1, 1024, 0, stream>>>(ncur, noff, N);
    hipMemcpyAsync(ecur, eoff, (size_t)M * 4, hipMemcpyDeviceToDevice, stream);
    hipMemcpyAsync(ncur, noff, (size_t)N * 4, hipMemcpyDeviceToDevice, stream);
    fill_kernel<<<(NNZ + 255) / 256, 256, 0, stream>>>(V, E, ecur, ncur, edge_v, node_e, NNZ);

    // ---- layer 0 (K=128) -> h1 ; layer 1 (K=256) -> h1 (in place) ----
    run_layer(X, 128, Wx0, bx0, Wv0, bv0, a0, Wt0, bt0, S,
              Xinit, Xfeat, Yv2e, Ybuf, wbuf, score,
              eoff, edge_v, noff, node_e, h1, N, M, NNZ, stream);
    run_layer(h1, 256, Wx1, bx1, Wv1, bv1, a1, Wt1, bt1, S,
              Xinit, Xfeat, Yv2e, Ybuf, wbuf, score,
              eoff, edge_v, noff, node_e, h1, N, M, NNZ, stream);

    // ---- hyperconv ----
    float* Xc = Xfeat;   // [N,128]
    float* Yh = Ybuf;    // [M,128]
    dim3 gC((N + TM - 1) / TM, 128 / TN);
    gemm_bias_kernel<<<gC, 256, 0, stream>>>(h1, Wf, bf, Xc, N, 128, 256, 0);
    deinv_kernel<<<(M + 255) / 256, 256, 0, stream>>>(eoff, edge_v, noff, Deinv, M);
    yh_kernel<<<(M + 3) / 4, 256, 0, stream>>>(Xc, eoff, edge_v, Deinv, Yh, M);
    xo_final_kernel<<<(N + 3) / 4, 256, 0, stream>>>(Yh, noff, node_e, (float*)d_out, N);
}

// Round 3
// 1046.811 us; speedup vs baseline: 6.5909x; 1.1096x over previous
//
#include <hip/hip_runtime.h>
#include <hip/hip_bf16.h>

typedef unsigned short u16;
typedef __attribute__((ext_vector_type(4))) u16 u16x4;
typedef __attribute__((ext_vector_type(8))) __bf16 bf16x8;
typedef __attribute__((ext_vector_type(4))) float f32x4;

__device__ __forceinline__ u16 f2bf(float x) {
    unsigned u = __float_as_uint(x);
    unsigned r = u + 0x7FFF + ((u >> 16) & 1);
    return (u16)(r >> 16);
}
__device__ __forceinline__ float bf2f(u16 h) {
    return __uint_as_float(((unsigned)h) << 16);
}

__device__ __forceinline__ void gl_lds16(const void* g, void* l) {
    __builtin_amdgcn_global_load_lds(
        (const __attribute__((address_space(1))) void*)g,
        (__attribute__((address_space(3))) void*)l, 16, 0, 0);
}

// =============== split-bf16 MFMA GEMM ===============
// C[M,Nc] = A[M,K] @ B^T[Nc,K]  with A,B given as (hi,lo) bf16 pairs.
// acc = Ahi*Bhi + Ahi*Blo + Alo*Bhi  (lo*lo dropped, ~2^-16 relative)
__global__ __launch_bounds__(256) void gemm_mfma_kernel(
    const u16* __restrict__ Ahi, const u16* __restrict__ Alo, int lda,
    const u16* __restrict__ Bhi, const u16* __restrict__ Blo, int ldb,
    const float* __restrict__ bias, float* __restrict__ C,
    int M, int Nc, int K, int accum)
{
    __shared__ __align__(16) u16 lds[4 * 4096];
    u16* sAhi = lds;
    u16* sAlo = lds + 4096;
    u16* sBhi = lds + 8192;
    u16* sBlo = lds + 12288;

    int tid = threadIdx.x;
    int wave = tid >> 6, lane = tid & 63;
    int row0 = blockIdx.x * 128, col0 = blockIdx.y * 128;

    // staging: two rounds of 64 rows (4 waves x 16 rows), 16B per lane,
    // global chunk XOR-swizzled so frag ds_read_b128 is ~conflict-free
    long gA[2], gB[2];
    int sOff[2];
#pragma unroll
    for (int r = 0; r < 2; ++r) {
        int trow = r * 64 + wave * 16 + (lane >> 2);
        int chunk = (lane & 3) ^ ((trow >> 2) & 3);
        int arow = min(row0 + trow, M - 1);
        gA[r] = (long)arow * lda + chunk * 8;
        gB[r] = (long)(col0 + trow) * ldb + chunk * 8;
        sOff[r] = (r * 64 + wave * 16) * 32;   // wave-uniform LDS base (ushorts)
    }

    int m16 = lane & 15, quad = lane >> 4;
    int offA[4], offB[4];
#pragma unroll
    for (int i = 0; i < 4; ++i) {
        int ra = (wave & 1) * 64 + i * 16 + m16;
        offA[i] = ra * 32 + ((quad ^ ((ra >> 2) & 3)) * 8);
        int rb = (wave >> 1) * 64 + i * 16 + m16;
        offB[i] = rb * 32 + ((quad ^ ((rb >> 2) & 3)) * 8);
    }

    f32x4 acc[4][4];
#pragma unroll
    for (int i = 0; i < 4; ++i)
#pragma unroll
        for (int j = 0; j < 4; ++j) {
            f32x4 z = {0.f, 0.f, 0.f, 0.f};
            acc[i][j] = z;
        }

    int nkb = K >> 5;
    for (int kb = 0; kb < nkb; ++kb) {
#pragma unroll
        for (int r = 0; r < 2; ++r) {
            gl_lds16(Ahi + gA[r], sAhi + sOff[r]);
            gl_lds16(Alo + gA[r], sAlo + sOff[r]);
            gl_lds16(Bhi + gB[r], sBhi + sOff[r]);
            gl_lds16(Blo + gB[r], sBlo + sOff[r]);
        }
        __syncthreads();
        bf16x8 ah[4], al[4], bh[4], bl[4];
#pragma unroll
        for (int i = 0; i < 4; ++i) {
            ah[i] = *(const bf16x8*)(sAhi + offA[i]);
            al[i] = *(const bf16x8*)(sAlo + offA[i]);
            bh[i] = *(const bf16x8*)(sBhi + offB[i]);
            bl[i] = *(const bf16x8*)(sBlo + offB[i]);
        }
#pragma unroll
        for (int i = 0; i < 4; ++i)
#pragma unroll
            for (int j = 0; j < 4; ++j) {
                acc[i][j] = __builtin_amdgcn_mfma_f32_16x16x32_bf16(ah[i], bh[j], acc[i][j], 0, 0, 0);
                acc[i][j] = __builtin_amdgcn_mfma_f32_16x16x32_bf16(ah[i], bl[j], acc[i][j], 0, 0, 0);
                acc[i][j] = __builtin_amdgcn_mfma_f32_16x16x32_bf16(al[i], bh[j], acc[i][j], 0, 0, 0);
            }
        __syncthreads();
#pragma unroll
        for (int r = 0; r < 2; ++r) { gA[r] += 32; gB[r] += 32; }
    }

    // epilogue: D row = quad*4 + reg, col = lane&15  (m89-verified layout)
    int wm = (wave & 1) * 64, wn = (wave >> 1) * 64;
#pragma unroll
    for (int j = 0; j < 4; ++j) {
        int col = col0 + wn + j * 16 + m16;
        float bj = accum ? 0.f : bias[col];
#pragma unroll
        for (int i = 0; i < 4; ++i) {
#pragma unroll
            for (int rr = 0; rr < 4; ++rr) {
                int row = row0 + wm + i * 16 + quad * 4 + rr;
                if (row < M) {
                    size_t idx = (size_t)row * Nc + col;
                    float v = acc[i][j][rr] + bj;
                    if (accum) v += C[idx];
                    C[idx] = v;
                }
            }
        }
    }
}

// =============== conversion kernels ===============
// fp32 -> (hi,lo) bf16, row-major, 4 elems/thread
__global__ void split4_kernel(const float* __restrict__ src, u16* __restrict__ hi,
                              u16* __restrict__ lo, int n4)
{
    int i = blockIdx.x * blockDim.x + threadIdx.x;
    if (i >= n4) return;
    float4 x = ((const float4*)src)[i];
    u16x4 h, l;
    h.x = f2bf(x.x); l.x = f2bf(x.x - bf2f(h.x));
    h.y = f2bf(x.y); l.y = f2bf(x.y - bf2f(h.y));
    h.z = f2bf(x.z); l.z = f2bf(x.z - bf2f(h.z));
    h.w = f2bf(x.w); l.w = f2bf(x.w - bf2f(h.w));
    *(u16x4*)(hi + (size_t)i * 4) = h;
    *(u16x4*)(lo + (size_t)i * 4) = l;
}

// W[K,Nc] fp32 -> W^T (hi,lo) bf16 [Nc,K].  Nc = 2^ncShift.
__global__ void wsplitT_kernel(const float* __restrict__ W, u16* __restrict__ Whi,
                               u16* __restrict__ Wlo, int K, int ncShift)
{
    int Nc = 1 << ncShift;
    int idx = blockIdx.x * blockDim.x + threadIdx.x;
    if (idx >= K * Nc) return;
    int k = idx >> ncShift, n = idx & (Nc - 1);
    float x = W[idx];
    u16 h = f2bf(x);
    u16 l = f2bf(x - bf2f(h));
    Whi[(size_t)n * K + k] = h;
    Wlo[(size_t)n * K + k] = l;
}

// =============== CSR build ===============
__global__ void count_kernel(const int* __restrict__ V, const int* __restrict__ E,
                             int* ecnt, int* ncnt, int nnz)
{
    int k = blockIdx.x * blockDim.x + threadIdx.x;
    if (k >= nnz) return;
    atomicAdd(&ecnt[E[k]], 1);
    atomicAdd(&ncnt[V[k]], 1);
}

__global__ __launch_bounds__(1024) void scan_kernel(const int* __restrict__ cnt,
                                                    int* __restrict__ off, int n)
{
    __shared__ int part[1024];
    int t = threadIdx.x;
    int chunk = (n + 1023) / 1024;
    int s0 = t * chunk;
    int s1 = min(n, s0 + chunk);
    int sum = 0;
    for (int i = s0; i < s1; ++i) sum += cnt[i];
    part[t] = sum;
    __syncthreads();
    for (int o = 1; o < 1024; o <<= 1) {
        int v = (t >= o) ? part[t - o] : 0;
        __syncthreads();
        part[t] += v;
        __syncthreads();
    }
    int base = (t > 0) ? part[t - 1] : 0;
    if (t == 0) off[0] = 0;
    for (int i = s0; i < s1; ++i) { base += cnt[i]; off[i + 1] = base; }
}

__global__ void fill_kernel(const int* __restrict__ V, const int* __restrict__ E,
                            int* ecur, int* ncur, int* edge_v, int* node_e, int nnz)
{
    int k = blockIdx.x * blockDim.x + threadIdx.x;
    if (k >= nnz) return;
    int v = V[k], e = E[k];
    int j = atomicAdd(&ecur[e], 1);
    edge_v[j] = v;
    int i = atomicAdd(&ncur[v], 1);
    node_e[i] = e;
}

// =============== graph kernels ===============
__global__ void score_kernel(const float* __restrict__ Xf, const float* __restrict__ a,
                             float* __restrict__ score, int N)
{
    int row = blockIdx.x * (blockDim.x >> 6) + (threadIdx.x >> 6);
    int lane = threadIdx.x & 63;
    if (row >= N) return;
    float4 x = *(const float4*)(Xf + (size_t)row * 256 + lane * 4);
    float4 av = *(const float4*)(a + lane * 4);
    float p = x.x * av.x + x.y * av.y + x.z * av.z + x.w * av.w;
#pragma unroll
    for (int off = 32; off; off >>= 1) p += __shfl_down(p, off);
    if (lane == 0) score[row] = p;
}

__global__ void edge_softmax_kernel(const float* __restrict__ score,
                                    const int* __restrict__ eoff,
                                    const int* __restrict__ edge_v,
                                    float* __restrict__ w, int M)
{
    int e = blockIdx.x * 4 + (threadIdx.x >> 6);
    if (e >= M) return;
    int lane = threadIdx.x & 63;
    int j0 = eoff[e], j1 = eoff[e + 1];
    if (j0 == j1) return;
    float m = -INFINITY;
    for (int j = j0 + lane; j < j1; j += 64) {
        float s = score[edge_v[j]];
        s = s >= 0.f ? s : 0.2f * s;
        m = fmaxf(m, s);
    }
#pragma unroll
    for (int o = 32; o; o >>= 1) m = fmaxf(m, __shfl_xor(m, o));
    float sum = 0.f;
    for (int j = j0 + lane; j < j1; j += 64) {
        float s = score[edge_v[j]];
        s = s >= 0.f ? s : 0.2f * s;
        sum += expf(s - m);
    }
#pragma unroll
    for (int o = 32; o; o >>= 1) sum += __shfl_xor(sum, o);
    float inv = 1.0f / sum;
    for (int j = j0 + lane; j < j1; j += 64) {
        float s = score[edge_v[j]];
        s = s >= 0.f ? s : 0.2f * s;
        w[j] = expf(s - m) * inv;
    }
}

// Yv[e,:] = elu(sum_j Xf[edge_v[j],:]*w[j]) -> written directly as (hi,lo) bf16
__global__ void v2e_gather_kernel(const float* __restrict__ Xf,
                                  const int* __restrict__ eoff,
                                  const int* __restrict__ edge_v,
                                  const float* __restrict__ w,
                                  u16* __restrict__ Yhi, u16* __restrict__ Ylo, int M)
{
    int e = blockIdx.x * 4 + (threadIdx.x >> 6);
    if (e >= M) return;
    int lane = threadIdx.x & 63;
    int j0 = eoff[e], j1 = eoff[e + 1];
    float4 acc = make_float4(0.f, 0.f, 0.f, 0.f);
    for (int j = j0; j < j1; ++j) {
        int v = edge_v[j];
        float ww = w[j];
        float4 x = *(const float4*)(Xf + (size_t)v * 256 + lane * 4);
        acc.x += x.x * ww; acc.y += x.y * ww;
        acc.z += x.z * ww; acc.w += x.w * ww;
    }
    acc.x = acc.x > 0.f ? acc.x : expm1f(acc.x);
    acc.y = acc.y > 0.f ? acc.y : expm1f(acc.y);
    acc.z = acc.z > 0.f ? acc.z : expm1f(acc.z);
    acc.w = acc.w > 0.f ? acc.w : expm1f(acc.w);
    u16x4 h, l;
    h.x = f2bf(acc.x); l.x = f2bf(acc.x - bf2f(h.x));
    h.y = f2bf(acc.y); l.y = f2bf(acc.y - bf2f(h.y));
    h.z = f2bf(acc.z); l.z = f2bf(acc.z - bf2f(h.z));
    h.w = f2bf(acc.w); l.w = f2bf(acc.w - bf2f(h.w));
    size_t base = (size_t)e * 256 + lane * 4;
    *(u16x4*)(Yhi + base) = h;
    *(u16x4*)(Ylo + base) = l;
}

// h[v,:] = elu(mean_i Y[node_e[i],:]) + Xinit[v,:] -> written as (hi,lo) bf16
__global__ void e2v_finish_kernel(const float* __restrict__ Y,
                                  const int* __restrict__ noff,
                                  const int* __restrict__ node_e,
                                  const float* __restrict__ Xinit,
                                  u16* __restrict__ Hhi, u16* __restrict__ Hlo, int N)
{
    int v = blockIdx.x * 4 + (threadIdx.x >> 6);
    if (v >= N) return;
    int lane = threadIdx.x & 63;
    int i0 = noff[v], i1 = noff[v + 1];
    float4 acc = make_float4(0.f, 0.f, 0.f, 0.f);
    for (int i = i0; i < i1; ++i) {
        int e = node_e[i];
        float4 y = *(const float4*)(Y + (size_t)e * 256 + lane * 4);
        acc.x += y.x; acc.y += y.y; acc.z += y.z; acc.w += y.w;
    }
    float inv = (i1 > i0) ? 1.0f / (float)(i1 - i0) : 0.f;
    size_t base = (size_t)v * 256 + lane * 4;
    float4 xi = *(const float4*)(Xinit + base);
    float o[4], m;
    m = acc.x * inv; o[0] = (m > 0.f ? m : expm1f(m)) + xi.x;
    m = acc.y * inv; o[1] = (m > 0.f ? m : expm1f(m)) + xi.y;
    m = acc.z * inv; o[2] = (m > 0.f ? m : expm1f(m)) + xi.z;
    m = acc.w * inv; o[3] = (m > 0.f ? m : expm1f(m)) + xi.w;
    u16x4 h, l;
    h.x = f2bf(o[0]); l.x = f2bf(o[0] - bf2f(h.x));
    h.y = f2bf(o[1]); l.y = f2bf(o[1] - bf2f(h.y));
    h.z = f2bf(o[2]); l.z = f2bf(o[2] - bf2f(h.z));
    h.w = f2bf(o[3]); l.w = f2bf(o[3] - bf2f(h.w));
    *(u16x4*)(Hhi + base) = h;
    *(u16x4*)(Hlo + base) = l;
}

// =============== hyperconv ===============
__global__ void deinv_kernel(const int* __restrict__ eoff, const int* __restrict__ edge_v,
                             const int* __restrict__ noff, float* __restrict__ Deinv, int M)
{
    int e = blockIdx.x * blockDim.x + threadIdx.x;
    if (e >= M) return;
    int j0 = eoff[e], j1 = eoff[e + 1];
    float s = 0.f;
    for (int j = j0; j < j1; ++j) {
        int v = edge_v[j];
        s += (float)(noff[v + 1] - noff[v]);
    }
    float De = s / ((float)(j1 - j0) + 1.0f);
    Deinv[e] = De > 0.f ? rsqrtf(De) : 1.0f;
}

__global__ void yh_kernel(const float* __restrict__ Xc,
                          const int* __restrict__ eoff, const int* __restrict__ edge_v,
                          const float* __restrict__ Deinv, float* __restrict__ Yh, int M)
{
    int e = blockIdx.x * 4 + (threadIdx.x >> 6);
    if (e >= M) return;
    int lane = threadIdx.x & 63;
    int j0 = eoff[e], j1 = eoff[e + 1];
    float2 acc = make_float2(0.f, 0.f);
    for (int j = j0; j < j1; ++j) {
        int v = edge_v[j];
        float2 x = *(const float2*)(Xc + (size_t)v * 128 + lane * 2);
        acc.x += x.x; acc.y += x.y;
    }
    float sc = ((j1 > j0) ? 1.0f / (float)(j1 - j0) : 0.f) * Deinv[e];
    float* d = Yh + (size_t)e * 128 + lane * 2;
    d[0] = acc.x * sc;
    d[1] = acc.y * sc;
}

__global__ void xo_final_kernel(const float* __restrict__ Yh,
                                const int* __restrict__ noff, const int* __restrict__ node_e,
                                float* __restrict__ out, int N)
{
    int v = blockIdx.x * 4 + (threadIdx.x >> 6);
    if (v >= N) return;
    int lane = threadIdx.x & 63;
    int i0 = noff[v], i1 = noff[v + 1];
    float2 acc = make_float2(0.f, 0.f);
    for (int i = i0; i < i1; ++i) {
        int e = node_e[i];
        float2 y = *(const float2*)(Yh + (size_t)e * 128 + lane * 2);
        acc.x += y.x; acc.y += y.y;
    }
    float sc = (i1 > i0) ? rsqrtf((float)(i1 - i0)) : 0.f;
    float* d = out + (size_t)v * 128 + lane * 2;
    d[0] = acc.x * sc;
    d[1] = acc.y * sc;
}

// =============== host-side ===============
static void gemm(const u16* Ahi, const u16* Alo, int lda,
                 const u16* Bhi, const u16* Blo, int ldb,
                 const float* bias, float* C, int M, int Nc, int K, int accum,
                 hipStream_t stream)
{
    dim3 g((M + 127) / 128, Nc / 128);
    gemm_mfma_kernel<<<g, 256, 0, stream>>>(Ahi, Alo, lda, Bhi, Blo, ldb, bias, C, M, Nc, K, accum);
}

static void run_layer(u16* Ahi, u16* Alo, int K,
                      const u16* WxThi, const u16* WxTlo, const float* bx,
                      const u16* WvThi, const u16* WvTlo, const float* bv,
                      const float* a,
                      const u16* WtThi, const u16* WtTlo, const float* bt,
                      const u16* Shi, const u16* Slo,
                      float* Xinit, float* Xfeat, float* Ybuf,
                      float* wbuf, float* score,
                      const int* eoff, const int* edge_v,
                      const int* noff, const int* node_e,
                      int N, int M, hipStream_t stream)
{
    gemm(Ahi, Alo, K, WxThi, WxTlo, K, bx, Xinit, N, 256, K, 0, stream);
    gemm(Ahi, Alo, K, WvThi, WvTlo, K, bv, Xfeat, N, 256, K, 0, stream);
    score_kernel<<<(N + 3) / 4, 256, 0, stream>>>(Xfeat, a, score, N);
    edge_softmax_kernel<<<(M + 3) / 4, 256, 0, stream>>>(score, eoff, edge_v, wbuf, M);
    // Yv (hi,lo) overwrites A-split region (dead after the two GEMMs above)
    v2e_gather_kernel<<<(M + 3) / 4, 256, 0, stream>>>(Xfeat, eoff, edge_v, wbuf, Ahi, Alo, M);
    gemm(Ahi, Alo, 256, WtThi, WtTlo, 320, bt, Ybuf, M, 256, 256, 0, stream);
    gemm(Shi, Slo, 64, WtThi + 256, WtTlo + 256, 320, nullptr, Ybuf, M, 256, 64, 1, stream);
    // h (hi,lo) overwrites A-split region (Yv dead after its GEMM)
    e2v_finish_kernel<<<(N + 3) / 4, 256, 0, stream>>>(Ybuf, noff, node_e, Xinit, Ahi, Alo, N);
}

extern "C" void kernel_launch(void* const* d_in, const int* in_sizes, int n_in,
                              void* d_out, int out_size, void* d_ws, size_t ws_size,
                              hipStream_t stream)
{
    const float* X   = (const float*)d_in[0];
    const int*   V   = (const int*)d_in[1];
    const int*   E   = (const int*)d_in[2];
    const float* S   = (const float*)d_in[3];
    const float* Wx0 = (const float*)d_in[4];  const float* bx0 = (const float*)d_in[5];
    const float* Wv0 = (const float*)d_in[6];  const float* bv0 = (const float*)d_in[7];
    const float* a0  = (const float*)d_in[8];
    const float* Wt0 = (const float*)d_in[9];  const float* bt0 = (const float*)d_in[10];
    const float* Wx1 = (const float*)d_in[11]; const float* bx1 = (const float*)d_in[12];
    const float* Wv1 = (const float*)d_in[13]; const float* bv1 = (const float*)d_in[14];
    const float* a1  = (const float*)d_in[15];
    const float* Wt1 = (const float*)d_in[16]; const float* bt1 = (const float*)d_in[17];
    const float* Wf  = (const float*)d_in[18]; const float* bf  = (const float*)d_in[19];

    int N   = in_sizes[0] / 128;
    int NNZ = in_sizes[1];
    int M   = in_sizes[3] / 64;

    float* ws = (float*)d_ws;
    size_t off = 0;
    float* Xinit = ws + off; off += (size_t)N * 256;
    float* Xfeat = ws + off; off += (size_t)N * 256;   // also Xc [N,128] in hyperconv
    float* Ybuf  = ws + off; off += (size_t)M * 256;   // also Yh [M,128]
    u16* Ahi = (u16*)(ws + off); off += (size_t)N * 128;   // N*256 ushorts
    u16* Alo = (u16*)(ws + off); off += (size_t)N * 128;
    u16* Shi = (u16*)(ws + off); off += (size_t)M * 32;    // M*64 ushorts
    u16* Slo = (u16*)(ws + off); off += (size_t)M * 32;
    // transposed split weights (hi,lo interleaved per matrix)
    u16* WxT0h = (u16*)(ws + off); off += (size_t)(256 * 128) / 2;
    u16* WxT0l = (u16*)(ws + off); off += (size_t)(256 * 128) / 2;
    u16* WvT0h = (u16*)(ws + off); off += (size_t)(256 * 128) / 2;
    u16* WvT0l = (u16*)(ws + off); off += (size_t)(256 * 128) / 2;
    u16* WtT0h = (u16*)(ws + off); off += (size_t)(256 * 320) / 2;
    u16* WtT0l = (u16*)(ws + off); off += (size_t)(256 * 320) / 2;
    u16* WxT1h = (u16*)(ws + off); off += (size_t)(256 * 256) / 2;
    u16* WxT1l = (u16*)(ws + off); off += (size_t)(256 * 256) / 2;
    u16* WvT1h = (u16*)(ws + off); off += (size_t)(256 * 256) / 2;
    u16* WvT1l = (u16*)(ws + off); off += (size_t)(256 * 256) / 2;
    u16* WtT1h = (u16*)(ws + off); off += (size_t)(256 * 320) / 2;
    u16* WtT1l = (u16*)(ws + off); off += (size_t)(256 * 320) / 2;
    u16* WfTh  = (u16*)(ws + off); off += (size_t)(128 * 256) / 2;
    u16* WfTl  = (u16*)(ws + off); off += (size_t)(128 * 256) / 2;
    float* wbuf  = ws + off; off += (size_t)NNZ;
    float* score = ws + off; off += (size_t)N;
    float* Deinv = ws + off; off += (size_t)M;
    int* eoff   = (int*)(ws + off); off += (size_t)(M + 1);
    int* ecur   = (int*)(ws + off); off += (size_t)M;
    int* edge_v = (int*)(ws + off); off += (size_t)NNZ;
    int* noff   = (int*)(ws + off); off += (size_t)(N + 1);
    int* ncur   = (int*)(ws + off); off += (size_t)N;
    int* node_e = (int*)(ws + off); off += (size_t)NNZ;

    // ---- CSR build ----
    hipMemsetAsync(ecur, 0, (size_t)M * 4, stream);
    hipMemsetAsync(ncur, 0, (size_t)N * 4, stream);
    count_kernel<<<(NNZ + 255) / 256, 256, 0, stream>>>(V, E, ecur, ncur, NNZ);
    scan_kernel<<<1, 1024, 0, stream>>>(ecur, eoff, M);
    scan_kernel<<<1, 1024, 0, stream>>>(ncur, noff, N);
    hipMemcpyAsync(ecur, eoff, (size_t)M * 4, hipMemcpyDeviceToDevice, stream);
    hipMemcpyAsync(ncur, noff, (size_t)N * 4, hipMemcpyDeviceToDevice, stream);
    fill_kernel<<<(NNZ + 255) / 256, 256, 0, stream>>>(V, E, ecur, ncur, edge_v, node_e, NNZ);

    // ---- input splits ----
    split4_kernel<<<((N * 128 / 4) + 255) / 256, 256, 0, stream>>>(X, Ahi, Alo, N * 128 / 4);
    split4_kernel<<<((M * 64 / 4) + 255) / 256, 256, 0, stream>>>(S, Shi, Slo, M * 64 / 4);

    // ---- weight transpose+split ----
    wsplitT_kernel<<<(128 * 256 + 255) / 256, 256, 0, stream>>>(Wx0, WxT0h, WxT0l, 128, 8);
    wsplitT_kernel<<<(128 * 256 + 255) / 256, 256, 0, stream>>>(Wv0, WvT0h, WvT0l, 128, 8);
    wsplitT_kernel<<<(320 * 256 + 255) / 256, 256, 0, stream>>>(Wt0, WtT0h, WtT0l, 320, 8);
    wsplitT_kernel<<<(256 * 256 + 255) / 256, 256, 0, stream>>>(Wx1, WxT1h, WxT1l, 256, 8);
    wsplitT_kernel<<<(256 * 256 + 255) / 256, 256, 0, stream>>>(Wv1, WvT1h, WvT1l, 256, 8);
    wsplitT_kernel<<<(320 * 256 + 255) / 256, 256, 0, stream>>>(Wt1, WtT1h, WtT1l, 320, 8);
    wsplitT_kernel<<<(256 * 128 + 255) / 256, 256, 0, stream>>>(Wf, WfTh, WfTl, 256, 7);

    // ---- layer 0 (K=128) ; layer 1 (K=256). h-split lands in Ahi/Alo. ----
    run_layer(Ahi, Alo, 128, WxT0h, WxT0l, bx0, WvT0h, WvT0l, bv0, a0,
              WtT0h, WtT0l, bt0, Shi, Slo, Xinit, Xfeat, Ybuf, wbuf, score,
              eoff, edge_v, noff, node_e, N, M, stream);
    run_layer(Ahi, Alo, 256, WxT1h, WxT1l, bx1, WvT1h, WvT1l, bv1, a1,
              WtT1h, WtT1l, bt1, Shi, Slo, Xinit, Xfeat, Ybuf, wbuf, score,
              eoff, edge_v, noff, node_e, N, M, stream);

    // ---- hyperconv: Xc = h2 @ Wf + bf ----
    float* Xc = Xfeat;
    float* Yh = Ybuf;
    gemm(Ahi, Alo, 256, WfTh, WfTl, 256, bf, Xc, N, 128, 256, 0, stream);
    deinv_kernel<<<(M + 255) / 256, 256, 0, stream>>>(eoff, edge_v, noff, Deinv, M);
    yh_kernel<<<(M + 3) / 4, 256, 0, stream>>>(Xc, eoff, edge_v, Deinv, Yh, M);
    xo_final_kernel<<<(N + 3) / 4, 256, 0, stream>>>(Yh, noff, node_e, (float*)d_out, N);
}

// Round 4
// 884.344 us; speedup vs baseline: 7.8017x; 1.1837x over previous
//
#include <hip/hip_runtime.h>
#include <hip/hip_bf16.h>

typedef unsigned short u16;
typedef __attribute__((ext_vector_type(4))) u16 u16x4;
typedef __attribute__((ext_vector_type(8))) __bf16 bf16x8;
typedef __attribute__((ext_vector_type(4))) float f32x4;

__device__ __forceinline__ u16 f2bf(float x) {
    unsigned u = __float_as_uint(x);
    unsigned r = u + 0x7FFF + ((u >> 16) & 1);
    return (u16)(r >> 16);
}
__device__ __forceinline__ float bf2f(u16 h) {
    return __uint_as_float(((unsigned)h) << 16);
}

__device__ __forceinline__ void gl_lds16(const void* g, void* l) {
    __builtin_amdgcn_global_load_lds(
        (const __attribute__((address_space(1))) void*)g,
        (__attribute__((address_space(3))) void*)l, 16, 0, 0);
}

// =============== split-bf16 MFMA GEMM ===============
// C[M,Nc] = A[M,K] @ B^T[Nc,K] + bias, A,B as (hi,lo) bf16 pairs.
// acc = Ahi*Bhi + Ahi*Blo + Alo*Bhi   (lo*lo dropped, ~2^-16 relative)
__global__ __launch_bounds__(256) void gemm_mfma_kernel(
    const u16* __restrict__ Ahi, const u16* __restrict__ Alo, int lda,
    const u16* __restrict__ Bhi, const u16* __restrict__ Blo, int ldb,
    const float* __restrict__ bias, float* __restrict__ C,
    int M, int Nc, int K)
{
    __shared__ __align__(16) u16 lds[4 * 4096];
    u16* sAhi = lds;
    u16* sAlo = lds + 4096;
    u16* sBhi = lds + 8192;
    u16* sBlo = lds + 12288;

    int tid = threadIdx.x;
    int wave = tid >> 6, lane = tid & 63;
    int row0 = blockIdx.x * 128, col0 = blockIdx.y * 128;

    long gA[2], gB[2];
    int sOff[2];
#pragma unroll
    for (int r = 0; r < 2; ++r) {
        int trow = r * 64 + wave * 16 + (lane >> 2);
        int chunk = (lane & 3) ^ ((trow >> 2) & 3);
        int arow = min(row0 + trow, M - 1);
        gA[r] = (long)arow * lda + chunk * 8;
        gB[r] = (long)(col0 + trow) * ldb + chunk * 8;
        sOff[r] = (r * 64 + wave * 16) * 32;
    }

    int m16 = lane & 15, quad = lane >> 4;
    int offA[4], offB[4];
#pragma unroll
    for (int i = 0; i < 4; ++i) {
        int ra = (wave & 1) * 64 + i * 16 + m16;
        offA[i] = ra * 32 + ((quad ^ ((ra >> 2) & 3)) * 8);
        int rb = (wave >> 1) * 64 + i * 16 + m16;
        offB[i] = rb * 32 + ((quad ^ ((rb >> 2) & 3)) * 8);
    }

    f32x4 acc[4][4];
#pragma unroll
    for (int i = 0; i < 4; ++i)
#pragma unroll
        for (int j = 0; j < 4; ++j) {
            f32x4 z = {0.f, 0.f, 0.f, 0.f};
            acc[i][j] = z;
        }

    int nkb = K >> 5;
    for (int kb = 0; kb < nkb; ++kb) {
#pragma unroll
        for (int r = 0; r < 2; ++r) {
            gl_lds16(Ahi + gA[r], sAhi + sOff[r]);
            gl_lds16(Alo + gA[r], sAlo + sOff[r]);
            gl_lds16(Bhi + gB[r], sBhi + sOff[r]);
            gl_lds16(Blo + gB[r], sBlo + sOff[r]);
        }
        __syncthreads();
        bf16x8 ah[4], al[4], bh[4], bl[4];
#pragma unroll
        for (int i = 0; i < 4; ++i) {
            ah[i] = *(const bf16x8*)(sAhi + offA[i]);
            al[i] = *(const bf16x8*)(sAlo + offA[i]);
            bh[i] = *(const bf16x8*)(sBhi + offB[i]);
            bl[i] = *(const bf16x8*)(sBlo + offB[i]);
        }
#pragma unroll
        for (int i = 0; i < 4; ++i)
#pragma unroll
            for (int j = 0; j < 4; ++j) {
                acc[i][j] = __builtin_amdgcn_mfma_f32_16x16x32_bf16(ah[i], bh[j], acc[i][j], 0, 0, 0);
                acc[i][j] = __builtin_amdgcn_mfma_f32_16x16x32_bf16(ah[i], bl[j], acc[i][j], 0, 0, 0);
                acc[i][j] = __builtin_amdgcn_mfma_f32_16x16x32_bf16(al[i], bh[j], acc[i][j], 0, 0, 0);
            }
        __syncthreads();
#pragma unroll
        for (int r = 0; r < 2; ++r) { gA[r] += 32; gB[r] += 32; }
    }

    int wm = (wave & 1) * 64, wn = (wave >> 1) * 64;
#pragma unroll
    for (int j = 0; j < 4; ++j) {
        int col = col0 + wn + j * 16 + m16;
        float bj = bias[col];
#pragma unroll
        for (int i = 0; i < 4; ++i) {
#pragma unroll
            for (int rr = 0; rr < 4; ++rr) {
                int row = row0 + wm + i * 16 + quad * 4 + rr;
                if (row < M) C[(size_t)row * Nc + col] = acc[i][j][rr] + bj;
            }
        }
    }
}

// =============== conversion kernels ===============
__global__ void split4_kernel(const float* __restrict__ src, u16* __restrict__ hi,
                              u16* __restrict__ lo, int n4)
{
    int i = blockIdx.x * blockDim.x + threadIdx.x;
    if (i >= n4) return;
    float4 x = ((const float4*)src)[i];
    u16x4 h, l;
    h.x = f2bf(x.x); l.x = f2bf(x.x - bf2f(h.x));
    h.y = f2bf(x.y); l.y = f2bf(x.y - bf2f(h.y));
    h.z = f2bf(x.z); l.z = f2bf(x.z - bf2f(h.z));
    h.w = f2bf(x.w); l.w = f2bf(x.w - bf2f(h.w));
    *(u16x4*)(hi + (size_t)i * 4) = h;
    *(u16x4*)(lo + (size_t)i * 4) = l;
}

// S[M,64] -> (hi,lo) into cols 256..319 of the [M,320]-strided edge A-buffer
__global__ void s_split_kernel(const float* __restrict__ S, u16* __restrict__ Aehi,
                               u16* __restrict__ Aelo, int M)
{
    int i = blockIdx.x * blockDim.x + threadIdx.x;
    if (i >= M * 64) return;
    int e = i >> 6, c = i & 63;
    float x = S[i];
    u16 h = f2bf(x);
    u16 l = f2bf(x - bf2f(h));
    Aehi[(size_t)e * 320 + 256 + c] = h;
    Aelo[(size_t)e * 320 + 256 + c] = l;
}

// W[K,Nc] fp32 -> W^T (hi,lo) bf16 [Nc,K].  Nc = 2^ncShift.
__global__ void wsplitT_kernel(const float* __restrict__ W, u16* __restrict__ Whi,
                               u16* __restrict__ Wlo, int K, int ncShift)
{
    int Nc = 1 << ncShift;
    int idx = blockIdx.x * blockDim.x + threadIdx.x;
    if (idx >= K * Nc) return;
    int k = idx >> ncShift, n = idx & (Nc - 1);
    float x = W[idx];
    u16 h = f2bf(x);
    u16 l = f2bf(x - bf2f(h));
    Whi[(size_t)n * K + k] = h;
    Wlo[(size_t)n * K + k] = l;
}

// =============== CSR build ===============
__global__ void count_kernel(const int* __restrict__ V, const int* __restrict__ E,
                             int* ecnt, int* ncnt, int nnz)
{
    int k = blockIdx.x * blockDim.x + threadIdx.x;
    if (k >= nnz) return;
    atomicAdd(&ecnt[E[k]], 1);
    atomicAdd(&ncnt[V[k]], 1);
}

// parallel scan, part 1: per-1024-chunk inclusive prefixes into off[i+1], chunk total into psum[b]
__global__ __launch_bounds__(256) void scan_part1(const int* __restrict__ cnt,
                                                  int* __restrict__ off,
                                                  int* __restrict__ psum, int n)
{
    __shared__ int tsum[256];
    int base = blockIdx.x * 1024;
    int t = threadIdx.x;
    int idx0 = base + t * 4;
    int4 c = make_int4(0, 0, 0, 0);
    if (idx0 + 3 < n) c = *(const int4*)(cnt + idx0);
    else {
        if (idx0 + 0 < n) c.x = cnt[idx0 + 0];
        if (idx0 + 1 < n) c.y = cnt[idx0 + 1];
        if (idx0 + 2 < n) c.z = cnt[idx0 + 2];
        if (idx0 + 3 < n) c.w = cnt[idx0 + 3];
    }
    int s = c.x + c.y + c.z + c.w;
    tsum[t] = s;
    __syncthreads();
    for (int o = 1; o < 256; o <<= 1) {
        int v = (t >= o) ? tsum[t - o] : 0;
        __syncthreads();
        tsum[t] += v;
        __syncthreads();
    }
    int run = tsum[t] - s;   // exclusive prefix within chunk
    run += c.x; if (idx0 + 0 < n) off[idx0 + 1] = run;
    run += c.y; if (idx0 + 1 < n) off[idx0 + 2] = run;
    run += c.z; if (idx0 + 2 < n) off[idx0 + 3] = run;
    run += c.w; if (idx0 + 3 < n) off[idx0 + 4] = run;
    if (t == 255) psum[blockIdx.x] = tsum[255];
}

// part 2: add chunk-prefix, finalize off, and emit fill cursors cur[i] = exclusive prefix
__global__ __launch_bounds__(256) void scan_part2(const int* __restrict__ cnt,
                                                  int* __restrict__ off,
                                                  const int* __restrict__ psum,
                                                  int* __restrict__ cur, int n)
{
    __shared__ int bpref;
    int t = threadIdx.x;
    int b = blockIdx.x;
    if (t < 64) {
        int s = (t < b) ? psum[t] : 0;     // nb <= 64 for n <= 65536
#pragma unroll
        for (int o = 32; o; o >>= 1) s += __shfl_xor(s, o);
        if (t == 0) {
            bpref = s;
            if (b == 0) off[0] = 0;
        }
    }
    __syncthreads();
    int base = b * 1024 + t * 4;
#pragma unroll
    for (int q = 0; q < 4; ++q) {
        int i = base + q;
        if (i < n) {
            int inc = off[i + 1] + bpref;
            off[i + 1] = inc;
            cur[i] = inc - cnt[i];
        }
    }
}

__global__ void fill_kernel(const int* __restrict__ V, const int* __restrict__ E,
                            int* ecur, int* ncur, int* edge_v, int* node_e, int nnz)
{
    int k = blockIdx.x * blockDim.x + threadIdx.x;
    if (k >= nnz) return;
    int v = V[k], e = E[k];
    int j = atomicAdd(&ecur[e], 1);
    edge_v[j] = v;
    int i = atomicAdd(&ncur[v], 1);
    node_e[i] = e;
}

// =============== graph kernels ===============
__global__ void score_kernel(const float* __restrict__ Xf, const float* __restrict__ a,
                             float* __restrict__ score, int N)
{
    int row = blockIdx.x * (blockDim.x >> 6) + (threadIdx.x >> 6);
    int lane = threadIdx.x & 63;
    if (row >= N) return;
    float4 x = *(const float4*)(Xf + (size_t)row * 256 + lane * 4);
    float4 av = *(const float4*)(a + lane * 4);
    float p = x.x * av.x + x.y * av.y + x.z * av.z + x.w * av.w;
#pragma unroll
    for (int off = 32; off; off >>= 1) p += __shfl_down(p, off);
    if (lane == 0) score[row] = p;
}

// fused segment softmax + weighted gather; writes elu result as (hi,lo) bf16
// into cols 0..255 of the [M,320]-strided edge A-buffer
__global__ void v2e_fused_kernel(const float* __restrict__ Xf,
                                 const float* __restrict__ score,
                                 const int* __restrict__ eoff,
                                 const int* __restrict__ edge_v,
                                 u16* __restrict__ Aehi, u16* __restrict__ Aelo, int M)
{
    int e = blockIdx.x * 4 + (threadIdx.x >> 6);
    if (e >= M) return;
    int lane = threadIdx.x & 63;
    int j0 = eoff[e], j1 = eoff[e + 1];
    float m = -INFINITY;
    for (int j = j0 + lane; j < j1; j += 64) {
        float s = score[edge_v[j]];
        s = s >= 0.f ? s : 0.2f * s;
        m = fmaxf(m, s);
    }
#pragma unroll
    for (int o = 32; o; o >>= 1) m = fmaxf(m, __shfl_xor(m, o));
    float sum = 0.f;
    for (int j = j0 + lane; j < j1; j += 64) {
        float s = score[edge_v[j]];
        s = s >= 0.f ? s : 0.2f * s;
        sum += expf(s - m);
    }
#pragma unroll
    for (int o = 32; o; o >>= 1) sum += __shfl_xor(sum, o);
    float inv = (j1 > j0) ? 1.0f / sum : 0.f;

    float4 acc = make_float4(0.f, 0.f, 0.f, 0.f);
    for (int j = j0; j < j1; ++j) {
        int v = edge_v[j];
        float s = score[v];
        s = s >= 0.f ? s : 0.2f * s;
        float ww = expf(s - m) * inv;
        float4 x = *(const float4*)(Xf + (size_t)v * 256 + lane * 4);
        acc.x += x.x * ww; acc.y += x.y * ww;
        acc.z += x.z * ww; acc.w += x.w * ww;
    }
    acc.x = acc.x > 0.f ? acc.x : expm1f(acc.x);
    acc.y = acc.y > 0.f ? acc.y : expm1f(acc.y);
    acc.z = acc.z > 0.f ? acc.z : expm1f(acc.z);
    acc.w = acc.w > 0.f ? acc.w : expm1f(acc.w);
    u16x4 h, l;
    h.x = f2bf(acc.x); l.x = f2bf(acc.x - bf2f(h.x));
    h.y = f2bf(acc.y); l.y = f2bf(acc.y - bf2f(h.y));
    h.z = f2bf(acc.z); l.z = f2bf(acc.z - bf2f(h.z));
    h.w = f2bf(acc.w); l.w = f2bf(acc.w - bf2f(h.w));
    size_t base = (size_t)e * 320 + lane * 4;
    *(u16x4*)(Aehi + base) = h;
    *(u16x4*)(Aelo + base) = l;
}

// h[v,:] = elu(mean_i Y[node_e[i],:]) + Xinit[v,:] -> (hi,lo) bf16
__global__ void e2v_finish_kernel(const float* __restrict__ Y,
                                  const int* __restrict__ noff,
                                  const int* __restrict__ node_e,
                                  const float* __restrict__ Xinit,
                                  u16* __restrict__ Hhi, u16* __restrict__ Hlo, int N)
{
    int v = blockIdx.x * 4 + (threadIdx.x >> 6);
    if (v >= N) return;
    int lane = threadIdx.x & 63;
    int i0 = noff[v], i1 = noff[v + 1];
    float4 acc = make_float4(0.f, 0.f, 0.f, 0.f);
    for (int i = i0; i < i1; ++i) {
        int e = node_e[i];
        float4 y = *(const float4*)(Y + (size_t)e * 256 + lane * 4);
        acc.x += y.x; acc.y += y.y; acc.z += y.z; acc.w += y.w;
    }
    float inv = (i1 > i0) ? 1.0f / (float)(i1 - i0) : 0.f;
    size_t base = (size_t)v * 256 + lane * 4;
    float4 xi = *(const float4*)(Xinit + base);
    float o[4], m;
    m = acc.x * inv; o[0] = (m > 0.f ? m : expm1f(m)) + xi.x;
    m = acc.y * inv; o[1] = (m > 0.f ? m : expm1f(m)) + xi.y;
    m = acc.z * inv; o[2] = (m > 0.f ? m : expm1f(m)) + xi.z;
    m = acc.w * inv; o[3] = (m > 0.f ? m : expm1f(m)) + xi.w;
    u16x4 h, l;
    h.x = f2bf(o[0]); l.x = f2bf(o[0] - bf2f(h.x));
    h.y = f2bf(o[1]); l.y = f2bf(o[1] - bf2f(h.y));
    h.z = f2bf(o[2]); l.z = f2bf(o[2] - bf2f(h.z));
    h.w = f2bf(o[3]); l.w = f2bf(o[3] - bf2f(h.w));
    *(u16x4*)(Hhi + base) = h;
    *(u16x4*)(Hlo + base) = l;
}

// =============== hyperconv ===============
__global__ void deinv_kernel(const int* __restrict__ eoff, const int* __restrict__ edge_v,
                             const int* __restrict__ noff, float* __restrict__ Deinv, int M)
{
    int e = blockIdx.x * blockDim.x + threadIdx.x;
    if (e >= M) return;
    int j0 = eoff[e], j1 = eoff[e + 1];
    float s = 0.f;
    for (int j = j0; j < j1; ++j) {
        int v = edge_v[j];
        s += (float)(noff[v + 1] - noff[v]);
    }
    float De = s / ((float)(j1 - j0) + 1.0f);
    Deinv[e] = De > 0.f ? rsqrtf(De) : 1.0f;
}

__global__ void yh_kernel(const float* __restrict__ Xc,
                          const int* __restrict__ eoff, const int* __restrict__ edge_v,
                          const float* __restrict__ Deinv, float* __restrict__ Yh, int M)
{
    int e = blockIdx.x * 4 + (threadIdx.x >> 6);
    if (e >= M) return;
    int lane = threadIdx.x & 63;
    int j0 = eoff[e], j1 = eoff[e + 1];
    float2 acc = make_float2(0.f, 0.f);
    for (int j = j0; j < j1; ++j) {
        int v = edge_v[j];
        float2 x = *(const float2*)(Xc + (size_t)v * 128 + lane * 2);
        acc.x += x.x; acc.y += x.y;
    }
    float sc = ((j1 > j0) ? 1.0f / (float)(j1 - j0) : 0.f) * Deinv[e];
    float* d = Yh + (size_t)e * 128 + lane * 2;
    d[0] = acc.x * sc;
    d[1] = acc.y * sc;
}

__global__ void xo_final_kernel(const float* __restrict__ Yh,
                                const int* __restrict__ noff, const int* __restrict__ node_e,
                                float* __restrict__ out, int N)
{
    int v = blockIdx.x * 4 + (threadIdx.x >> 6);
    if (v >= N) return;
    int lane = threadIdx.x & 63;
    int i0 = noff[v], i1 = noff[v + 1];
    float2 acc = make_float2(0.f, 0.f);
    for (int i = i0; i < i1; ++i) {
        int e = node_e[i];
        float2 y = *(const float2*)(Yh + (size_t)e * 128 + lane * 2);
        acc.x += y.x; acc.y += y.y;
    }
    float sc = (i1 > i0) ? rsqrtf((float)(i1 - i0)) : 0.f;
    float* d = out + (size_t)v * 128 + lane * 2;
    d[0] = acc.x * sc;
    d[1] = acc.y * sc;
}

// =============== host-side ===============
static void gemm(const u16* Ahi, const u16* Alo, int lda,
                 const u16* Bhi, const u16* Blo, int ldb,
                 const float* bias, float* C, int M, int Nc, int K,
                 hipStream_t stream)
{
    dim3 g((M + 127) / 128, Nc / 128);
    gemm_mfma_kernel<<<g, 256, 0, stream>>>(Ahi, Alo, lda, Bhi, Blo, ldb, bias, C, M, Nc, K);
}

static void run_layer(u16* Ahi, u16* Alo, int K,
                      const u16* WxThi, const u16* WxTlo, const float* bx,
                      const u16* WvThi, const u16* WvTlo, const float* bv,
                      const float* a,
                      const u16* WtThi, const u16* WtTlo, const float* bt,
                      u16* Aehi, u16* Aelo,
                      float* Xinit, float* Xfeat, float* Ybuf, float* score,
                      const int* eoff, const int* edge_v,
                      const int* noff, const int* node_e,
                      int N, int M, hipStream_t stream)
{
    gemm(Ahi, Alo, K, WxThi, WxTlo, K, bx, Xinit, N, 256, K, stream);
    gemm(Ahi, Alo, K, WvThi, WvTlo, K, bv, Xfeat, N, 256, K, stream);
    score_kernel<<<(N + 3) / 4, 256, 0, stream>>>(Xfeat, a, score, N);
    v2e_fused_kernel<<<(M + 3) / 4, 256, 0, stream>>>(Xfeat, score, eoff, edge_v, Aehi, Aelo, M);
    // Y = [Yv2e | S] @ Wt + bt  in one K=320 GEMM  (Ybuf aliases Xfeat, dead by now)
    gemm(Aehi, Aelo, 320, WtThi, WtTlo, 320, bt, Ybuf, M, 256, 320, stream);
    e2v_finish_kernel<<<(N + 3) / 4, 256, 0, stream>>>(Ybuf, noff, node_e, Xinit, Ahi, Alo, N);
}

extern "C" void kernel_launch(void* const* d_in, const int* in_sizes, int n_in,
                              void* d_out, int out_size, void* d_ws, size_t ws_size,
                              hipStream_t stream)
{
    const float* X   = (const float*)d_in[0];
    const int*   V   = (const int*)d_in[1];
    const int*   E   = (const int*)d_in[2];
    const float* S   = (const float*)d_in[3];
    const float* Wx0 = (const float*)d_in[4];  const float* bx0 = (const float*)d_in[5];
    const float* Wv0 = (const float*)d_in[6];  const float* bv0 = (const float*)d_in[7];
    const float* a0  = (const float*)d_in[8];
    const float* Wt0 = (const float*)d_in[9];  const float* bt0 = (const float*)d_in[10];
    const float* Wx1 = (const float*)d_in[11]; const float* bx1 = (const float*)d_in[12];
    const float* Wv1 = (const float*)d_in[13]; const float* bv1 = (const float*)d_in[14];
    const float* a1  = (const float*)d_in[15];
    const float* Wt1 = (const float*)d_in[16]; const float* bt1 = (const float*)d_in[17];
    const float* Wf  = (const float*)d_in[18]; const float* bf  = (const float*)d_in[19];

    int N   = in_sizes[0] / 128;
    int NNZ = in_sizes[1];
    int M   = in_sizes[3] / 64;

    float* ws = (float*)d_ws;
    size_t off = 0;
    float* Xinit = ws + off; off += (size_t)N * 256;   // also Yh [M,128] in hyperconv
    float* Xfeat = ws + off; off += (size_t)N * 256;   // also Ybuf [M,256]; also Xc [N,128]
    float* Ybuf  = Xfeat;
    u16* Ahi  = (u16*)(ws + off); off += (size_t)N * 128;  // N*256 u16
    u16* Alo  = (u16*)(ws + off); off += (size_t)N * 128;
    u16* Aehi = (u16*)(ws + off); off += (size_t)M * 160;  // M*320 u16
    u16* Aelo = (u16*)(ws + off); off += (size_t)M * 160;
    u16* WxT0h = (u16*)(ws + off); off += (size_t)(256 * 128) / 2;
    u16* WxT0l = (u16*)(ws + off); off += (size_t)(256 * 128) / 2;
    u16* WvT0h = (u16*)(ws + off); off += (size_t)(256 * 128) / 2;
    u16* WvT0l = (u16*)(ws + off); off += (size_t)(256 * 128) / 2;
    u16* WtT0h = (u16*)(ws + off); off += (size_t)(256 * 320) / 2;
    u16* WtT0l = (u16*)(ws + off); off += (size_t)(256 * 320) / 2;
    u16* WxT1h = (u16*)(ws + off); off += (size_t)(256 * 256) / 2;
    u16* WxT1l = (u16*)(ws + off); off += (size_t)(256 * 256) / 2;
    u16* WvT1h = (u16*)(ws + off); off += (size_t)(256 * 256) / 2;
    u16* WvT1l = (u16*)(ws + off); off += (size_t)(256 * 256) / 2;
    u16* WtT1h = (u16*)(ws + off); off += (size_t)(256 * 320) / 2;
    u16* WtT1l = (u16*)(ws + off); off += (size_t)(256 * 320) / 2;
    u16* WfTh  = (u16*)(ws + off); off += (size_t)(128 * 256) / 2;
    u16* WfTl  = (u16*)(ws + off); off += (size_t)(128 * 256) / 2;
    float* score = ws + off; off += (size_t)N;
    float* Deinv = ws + off; off += (size_t)M;
    int* eoff   = (int*)(ws + off); off += (size_t)(M + 1);
    int* ecnt   = (int*)(ws + off); off += (size_t)M;
    int* ecur   = (int*)(ws + off); off += (size_t)M;
    int* psumE  = (int*)(ws + off); off += 64;
    int* edge_v = (int*)(ws + off); off += (size_t)NNZ;
    int* noff   = (int*)(ws + off); off += (size_t)(N + 1);
    int* ncnt   = (int*)(ws + off); off += (size_t)N;
    int* ncur   = (int*)(ws + off); off += (size_t)N;
    int* psumN  = (int*)(ws + off); off += 64;
    int* node_e = (int*)(ws + off); off += (size_t)NNZ;

    // ---- CSR build (parallel scan) ----
    hipMemsetAsync(ecnt, 0, (size_t)M * 4, stream);
    hipMemsetAsync(ncnt, 0, (size_t)N * 4, stream);
    count_kernel<<<(NNZ + 255) / 256, 256, 0, stream>>>(V, E, ecnt, ncnt, NNZ);
    int nbE = (M + 1023) / 1024, nbN = (N + 1023) / 1024;
    scan_part1<<<nbE, 256, 0, stream>>>(ecnt, eoff, psumE, M);
    scan_part1<<<nbN, 256, 0, stream>>>(ncnt, noff, psumN, N);
    scan_part2<<<nbE, 256, 0, stream>>>(ecnt, eoff, psumE, ecur, M);
    scan_part2<<<nbN, 256, 0, stream>>>(ncnt, noff, psumN, ncur, N);
    fill_kernel<<<(NNZ + 255) / 256, 256, 0, stream>>>(V, E, ecur, ncur, edge_v, node_e, NNZ);

    // ---- input splits ----
    split4_kernel<<<((N * 128 / 4) + 255) / 256, 256, 0, stream>>>(X, Ahi, Alo, N * 128 / 4);
    s_split_kernel<<<((M * 64) + 255) / 256, 256, 0, stream>>>(S, Aehi, Aelo, M);

    // ---- weight transpose+split ----
    wsplitT_kernel<<<(128 * 256 + 255) / 256, 256, 0, stream>>>(Wx0, WxT0h, WxT0l, 128, 8);
    wsplitT_kernel<<<(128 * 256 + 255) / 256, 256, 0, stream>>>(Wv0, WvT0h, WvT0l, 128, 8);
    wsplitT_kernel<<<(320 * 256 + 255) / 256, 256, 0, stream>>>(Wt0, WtT0h, WtT0l, 320, 8);
    wsplitT_kernel<<<(256 * 256 + 255) / 256, 256, 0, stream>>>(Wx1, WxT1h, WxT1l, 256, 8);
    wsplitT_kernel<<<(256 * 256 + 255) / 256, 256, 0, stream>>>(Wv1, WvT1h, WvT1l, 256, 8);
    wsplitT_kernel<<<(320 * 256 + 255) / 256, 256, 0, stream>>>(Wt1, WtT1h, WtT1l, 320, 8);
    wsplitT_kernel<<<(256 * 128 + 255) / 256, 256, 0, stream>>>(Wf, WfTh, WfTl, 256, 7);

    // ---- layers ----
    run_layer(Ahi, Alo, 128, WxT0h, WxT0l, bx0, WvT0h, WvT0l, bv0, a0,
              WtT0h, WtT0l, bt0, Aehi, Aelo, Xinit, Xfeat, Ybuf, score,
              eoff, edge_v, noff, node_e, N, M, stream);
    run_layer(Ahi, Alo, 256, WxT1h, WxT1l, bx1, WvT1h, WvT1l, bv1, a1,
              WtT1h, WtT1l, bt1, Aehi, Aelo, Xinit, Xfeat, Ybuf, score,
              eoff, edge_v, noff, node_e, N, M, stream);

    // ---- hyperconv ----
    float* Xc = Xfeat;   // [N,128] (Ybuf dead)
    float* Yh = Xinit;   // [M,128] (Xinit dead)
    gemm(Ahi, Alo, 256, WfTh, WfTl, 256, bf, Xc, N, 128, 256, stream);
    deinv_kernel<<<(M + 255) / 256, 256, 0, stream>>>(eoff, edge_v, noff, Deinv, M);
    yh_kernel<<<(M + 3) / 4, 256, 0, stream>>>(Xc, eoff, edge_v, Deinv, Yh, M);
    xo_final_kernel<<<(N + 3) / 4, 256, 0, stream>>>(Yh, noff, node_e, (float*)d_out, N);
}

// Round 5
// 824.665 us; speedup vs baseline: 8.3663x; 1.0724x over previous
//
#include <hip/hip_runtime.h>
#include <hip/hip_bf16.h>

typedef unsigned short u16;
typedef __attribute__((ext_vector_type(4))) u16 u16x4;
typedef __attribute__((ext_vector_type(8))) __bf16 bf16x8;
typedef __attribute__((ext_vector_type(4))) float f32x4;

__device__ __forceinline__ u16 f2bf(float x) {
    unsigned u = __float_as_uint(x);
    unsigned r = u + 0x7FFF + ((u >> 16) & 1);
    return (u16)(r >> 16);
}
__device__ __forceinline__ float bf2f(u16 h) {
    return __uint_as_float(((unsigned)h) << 16);
}

__device__ __forceinline__ void gl_lds16(const void* g, void* l) {
    __builtin_amdgcn_global_load_lds(
        (const __attribute__((address_space(1))) void*)g,
        (__attribute__((address_space(3))) void*)l, 16, 0, 0);
}

// =============== split-bf16 MFMA GEMM ===============
// C[M,Nc] = A[M,K] @ B^T[Nc,K] + bias, A,B as (hi,lo) bf16 pairs.
// acc = Ahi*Bhi + Ahi*Blo + Alo*Bhi   (lo*lo dropped, ~2^-16 relative)
__global__ __launch_bounds__(256) void gemm_mfma_kernel(
    const u16* __restrict__ Ahi, const u16* __restrict__ Alo, int lda,
    const u16* __restrict__ Bhi, const u16* __restrict__ Blo, int ldb,
    const float* __restrict__ bias, float* __restrict__ C,
    int M, int Nc, int K)
{
    __shared__ __align__(16) u16 lds[4 * 4096];
    u16* sAhi = lds;
    u16* sAlo = lds + 4096;
    u16* sBhi = lds + 8192;
    u16* sBlo = lds + 12288;

    int tid = threadIdx.x;
    int wave = tid >> 6, lane = tid & 63;
    int row0 = blockIdx.x * 128, col0 = blockIdx.y * 128;

    long gA[2], gB[2];
    int sOff[2];
#pragma unroll
    for (int r = 0; r < 2; ++r) {
        int trow = r * 64 + wave * 16 + (lane >> 2);
        int chunk = (lane & 3) ^ ((trow >> 2) & 3);
        int arow = min(row0 + trow, M - 1);
        gA[r] = (long)arow * lda + chunk * 8;
        gB[r] = (long)(col0 + trow) * ldb + chunk * 8;
        sOff[r] = (r * 64 + wave * 16) * 32;
    }

    int m16 = lane & 15, quad = lane >> 4;
    int offA[4], offB[4];
#pragma unroll
    for (int i = 0; i < 4; ++i) {
        int ra = (wave & 1) * 64 + i * 16 + m16;
        offA[i] = ra * 32 + ((quad ^ ((ra >> 2) & 3)) * 8);
        int rb = (wave >> 1) * 64 + i * 16 + m16;
        offB[i] = rb * 32 + ((quad ^ ((rb >> 2) & 3)) * 8);
    }

    f32x4 acc[4][4];
#pragma unroll
    for (int i = 0; i < 4; ++i)
#pragma unroll
        for (int j = 0; j < 4; ++j) {
            f32x4 z = {0.f, 0.f, 0.f, 0.f};
            acc[i][j] = z;
        }

    int nkb = K >> 5;
    for (int kb = 0; kb < nkb; ++kb) {
#pragma unroll
        for (int r = 0; r < 2; ++r) {
            gl_lds16(Ahi + gA[r], sAhi + sOff[r]);
            gl_lds16(Alo + gA[r], sAlo + sOff[r]);
            gl_lds16(Bhi + gB[r], sBhi + sOff[r]);
            gl_lds16(Blo + gB[r], sBlo + sOff[r]);
        }
        __syncthreads();
        bf16x8 ah[4], al[4], bh[4], bl[4];
#pragma unroll
        for (int i = 0; i < 4; ++i) {
            ah[i] = *(const bf16x8*)(sAhi + offA[i]);
            al[i] = *(const bf16x8*)(sAlo + offA[i]);
            bh[i] = *(const bf16x8*)(sBhi + offB[i]);
            bl[i] = *(const bf16x8*)(sBlo + offB[i]);
        }
#pragma unroll
        for (int i = 0; i < 4; ++i)
#pragma unroll
            for (int j = 0; j < 4; ++j) {
                acc[i][j] = __builtin_amdgcn_mfma_f32_16x16x32_bf16(ah[i], bh[j], acc[i][j], 0, 0, 0);
                acc[i][j] = __builtin_amdgcn_mfma_f32_16x16x32_bf16(ah[i], bl[j], acc[i][j], 0, 0, 0);
                acc[i][j] = __builtin_amdgcn_mfma_f32_16x16x32_bf16(al[i], bh[j], acc[i][j], 0, 0, 0);
            }
        __syncthreads();
#pragma unroll
        for (int r = 0; r < 2; ++r) { gA[r] += 32; gB[r] += 32; }
    }

    int wm = (wave & 1) * 64, wn = (wave >> 1) * 64;
#pragma unroll
    for (int j = 0; j < 4; ++j) {
        int col = col0 + wn + j * 16 + m16;
        float bj = bias[col];
#pragma unroll
        for (int i = 0; i < 4; ++i) {
#pragma unroll
            for (int rr = 0; rr < 4; ++rr) {
                int row = row0 + wm + i * 16 + quad * 4 + rr;
                if (row < M) C[(size_t)row * Nc + col] = acc[i][j][rr] + bj;
            }
        }
    }
}

// =============== conversion kernels ===============
__global__ void split4_kernel(const float* __restrict__ src, u16* __restrict__ hi,
                              u16* __restrict__ lo, int n4)
{
    int i = blockIdx.x * blockDim.x + threadIdx.x;
    if (i >= n4) return;
    float4 x = ((const float4*)src)[i];
    u16x4 h, l;
    h.x = f2bf(x.x); l.x = f2bf(x.x - bf2f(h.x));
    h.y = f2bf(x.y); l.y = f2bf(x.y - bf2f(h.y));
    h.z = f2bf(x.z); l.z = f2bf(x.z - bf2f(h.z));
    h.w = f2bf(x.w); l.w = f2bf(x.w - bf2f(h.w));
    *(u16x4*)(hi + (size_t)i * 4) = h;
    *(u16x4*)(lo + (size_t)i * 4) = l;
}

// S[M,64] -> (hi,lo) into cols 256..319 of the [M,320]-strided edge A-buffer
__global__ void s_split_kernel(const float* __restrict__ S, u16* __restrict__ Aehi,
                               u16* __restrict__ Aelo, int M)
{
    int i = blockIdx.x * blockDim.x + threadIdx.x;
    if (i >= M * 64) return;
    int e = i >> 6, c = i & 63;
    float x = S[i];
    u16 h = f2bf(x);
    u16 l = f2bf(x - bf2f(h));
    Aehi[(size_t)e * 320 + 256 + c] = h;
    Aelo[(size_t)e * 320 + 256 + c] = l;
}

// W[K,Nc] fp32 -> W^T (hi,lo) bf16 [Nc,K].  Nc = 2^ncShift.
__global__ void wsplitT_kernel(const float* __restrict__ W, u16* __restrict__ Whi,
                               u16* __restrict__ Wlo, int K, int ncShift)
{
    int Nc = 1 << ncShift;
    int idx = blockIdx.x * blockDim.x + threadIdx.x;
    if (idx >= K * Nc) return;
    int k = idx >> ncShift, n = idx & (Nc - 1);
    float x = W[idx];
    u16 h = f2bf(x);
    u16 l = f2bf(x - bf2f(h));
    Whi[(size_t)n * K + k] = h;
    Wlo[(size_t)n * K + k] = l;
}

// =============== CSR build ===============
__global__ void count_kernel(const int* __restrict__ V, const int* __restrict__ E,
                             int* ecnt, int* ncnt, int nnz)
{
    int k = blockIdx.x * blockDim.x + threadIdx.x;
    if (k >= nnz) return;
    atomicAdd(&ecnt[E[k]], 1);
    atomicAdd(&ncnt[V[k]], 1);
}

__global__ __launch_bounds__(256) void scan_part1(const int* __restrict__ cnt,
                                                  int* __restrict__ off,
                                                  int* __restrict__ psum, int n)
{
    __shared__ int tsum[256];
    int base = blockIdx.x * 1024;
    int t = threadIdx.x;
    int idx0 = base + t * 4;
    int4 c = make_int4(0, 0, 0, 0);
    if (idx0 + 3 < n) c = *(const int4*)(cnt + idx0);
    else {
        if (idx0 + 0 < n) c.x = cnt[idx0 + 0];
        if (idx0 + 1 < n) c.y = cnt[idx0 + 1];
        if (idx0 + 2 < n) c.z = cnt[idx0 + 2];
        if (idx0 + 3 < n) c.w = cnt[idx0 + 3];
    }
    int s = c.x + c.y + c.z + c.w;
    tsum[t] = s;
    __syncthreads();
    for (int o = 1; o < 256; o <<= 1) {
        int v = (t >= o) ? tsum[t - o] : 0;
        __syncthreads();
        tsum[t] += v;
        __syncthreads();
    }
    int run = tsum[t] - s;
    run += c.x; if (idx0 + 0 < n) off[idx0 + 1] = run;
    run += c.y; if (idx0 + 1 < n) off[idx0 + 2] = run;
    run += c.z; if (idx0 + 2 < n) off[idx0 + 3] = run;
    run += c.w; if (idx0 + 3 < n) off[idx0 + 4] = run;
    if (t == 255) psum[blockIdx.x] = tsum[255];
}

__global__ __launch_bounds__(256) void scan_part2(const int* __restrict__ cnt,
                                                  int* __restrict__ off,
                                                  const int* __restrict__ psum,
                                                  int* __restrict__ cur, int n)
{
    __shared__ int bpref;
    int t = threadIdx.x;
    int b = blockIdx.x;
    if (t < 64) {
        int s = (t < b) ? psum[t] : 0;
#pragma unroll
        for (int o = 32; o; o >>= 1) s += __shfl_xor(s, o);
        if (t == 0) {
            bpref = s;
            if (b == 0) off[0] = 0;
        }
    }
    __syncthreads();
    int base = b * 1024 + t * 4;
#pragma unroll
    for (int q = 0; q < 4; ++q) {
        int i = base + q;
        if (i < n) {
            int inc = off[i + 1] + bpref;
            off[i + 1] = inc;
            cur[i] = inc - cnt[i];
        }
    }
}

__global__ void fill_kernel(const int* __restrict__ V, const int* __restrict__ E,
                            int* ecur, int* ncur, int* edge_v, int* node_e, int nnz)
{
    int k = blockIdx.x * blockDim.x + threadIdx.x;
    if (k >= nnz) return;
    int v = V[k], e = E[k];
    int j = atomicAdd(&ecur[e], 1);
    edge_v[j] = v;
    int i = atomicAdd(&ncur[v], 1);
    node_e[i] = e;
}

// =============== graph kernels ===============
__global__ void score_kernel(const float* __restrict__ Xf, const float* __restrict__ a,
                             float* __restrict__ score, int N)
{
    int row = blockIdx.x * (blockDim.x >> 6) + (threadIdx.x >> 6);
    int lane = threadIdx.x & 63;
    if (row >= N) return;
    float4 x = *(const float4*)(Xf + (size_t)row * 256 + lane * 4);
    float4 av = *(const float4*)(a + lane * 4);
    float p = x.x * av.x + x.y * av.y + x.z * av.z + x.w * av.w;
#pragma unroll
    for (int off = 32; off; off >>= 1) p += __shfl_down(p, off);
    if (lane == 0) score[row] = p;
}

__device__ __forceinline__ float lrelu(float s) { return s >= 0.f ? s : 0.2f * s; }

// fused segment softmax + weighted gather (4-wide MLP unroll); writes elu result
// as (hi,lo) bf16 into cols 0..255 of the [M,320]-strided edge A-buffer
__global__ void v2e_fused_kernel(const float* __restrict__ Xf,
                                 const float* __restrict__ score,
                                 const int* __restrict__ eoff,
                                 const int* __restrict__ edge_v,
                                 u16* __restrict__ Aehi, u16* __restrict__ Aelo, int M)
{
    int e = blockIdx.x * 4 + (threadIdx.x >> 6);
    if (e >= M) return;
    int lane = threadIdx.x & 63;
    int j0 = eoff[e], j1 = eoff[e + 1];
    float m = -INFINITY;
    for (int j = j0 + lane; j < j1; j += 64) m = fmaxf(m, lrelu(score[edge_v[j]]));
#pragma unroll
    for (int o = 32; o; o >>= 1) m = fmaxf(m, __shfl_xor(m, o));
    float sum = 0.f;
    for (int j = j0 + lane; j < j1; j += 64) sum += expf(lrelu(score[edge_v[j]]) - m);
#pragma unroll
    for (int o = 32; o; o >>= 1) sum += __shfl_xor(sum, o);
    float inv = (j1 > j0) ? 1.0f / sum : 0.f;

    float4 acc = make_float4(0.f, 0.f, 0.f, 0.f);
    int j = j0;
    for (; j + 3 < j1; j += 4) {
        int v0 = edge_v[j + 0], v1 = edge_v[j + 1], v2 = edge_v[j + 2], v3 = edge_v[j + 3];
        float s0 = score[v0], s1 = score[v1], s2 = score[v2], s3 = score[v3];
        float4 x0 = *(const float4*)(Xf + (size_t)v0 * 256 + lane * 4);
        float4 x1 = *(const float4*)(Xf + (size_t)v1 * 256 + lane * 4);
        float4 x2 = *(const float4*)(Xf + (size_t)v2 * 256 + lane * 4);
        float4 x3 = *(const float4*)(Xf + (size_t)v3 * 256 + lane * 4);
        float w0 = expf(lrelu(s0) - m) * inv;
        float w1 = expf(lrelu(s1) - m) * inv;
        float w2 = expf(lrelu(s2) - m) * inv;
        float w3 = expf(lrelu(s3) - m) * inv;
        acc.x += x0.x * w0; acc.y += x0.y * w0; acc.z += x0.z * w0; acc.w += x0.w * w0;
        acc.x += x1.x * w1; acc.y += x1.y * w1; acc.z += x1.z * w1; acc.w += x1.w * w1;
        acc.x += x2.x * w2; acc.y += x2.y * w2; acc.z += x2.z * w2; acc.w += x2.w * w2;
        acc.x += x3.x * w3; acc.y += x3.y * w3; acc.z += x3.z * w3; acc.w += x3.w * w3;
    }
    for (; j < j1; ++j) {
        int v = edge_v[j];
        float ww = expf(lrelu(score[v]) - m) * inv;
        float4 x = *(const float4*)(Xf + (size_t)v * 256 + lane * 4);
        acc.x += x.x * ww; acc.y += x.y * ww; acc.z += x.z * ww; acc.w += x.w * ww;
    }
    acc.x = acc.x > 0.f ? acc.x : expm1f(acc.x);
    acc.y = acc.y > 0.f ? acc.y : expm1f(acc.y);
    acc.z = acc.z > 0.f ? acc.z : expm1f(acc.z);
    acc.w = acc.w > 0.f ? acc.w : expm1f(acc.w);
    u16x4 h, l;
    h.x = f2bf(acc.x); l.x = f2bf(acc.x - bf2f(h.x));
    h.y = f2bf(acc.y); l.y = f2bf(acc.y - bf2f(h.y));
    h.z = f2bf(acc.z); l.z = f2bf(acc.z - bf2f(h.z));
    h.w = f2bf(acc.w); l.w = f2bf(acc.w - bf2f(h.w));
    size_t base = (size_t)e * 320 + lane * 4;
    *(u16x4*)(Aehi + base) = h;
    *(u16x4*)(Aelo + base) = l;
}

// h[v,:] = elu(mean_i Y[node_e[i],:]) + Xinit[v,:] -> (hi,lo) bf16  (4-wide unroll)
__global__ void e2v_finish_kernel(const float* __restrict__ Y,
                                  const int* __restrict__ noff,
                                  const int* __restrict__ node_e,
                                  const float* __restrict__ Xinit,
                                  u16* __restrict__ Hhi, u16* __restrict__ Hlo, int N)
{
    int v = blockIdx.x * 4 + (threadIdx.x >> 6);
    if (v >= N) return;
    int lane = threadIdx.x & 63;
    int i0 = noff[v], i1 = noff[v + 1];
    float4 acc = make_float4(0.f, 0.f, 0.f, 0.f);
    int i = i0;
    for (; i + 3 < i1; i += 4) {
        int e0 = node_e[i + 0], e1 = node_e[i + 1], e2 = node_e[i + 2], e3 = node_e[i + 3];
        float4 y0 = *(const float4*)(Y + (size_t)e0 * 256 + lane * 4);
        float4 y1 = *(const float4*)(Y + (size_t)e1 * 256 + lane * 4);
        float4 y2 = *(const float4*)(Y + (size_t)e2 * 256 + lane * 4);
        float4 y3 = *(const float4*)(Y + (size_t)e3 * 256 + lane * 4);
        acc.x += y0.x; acc.y += y0.y; acc.z += y0.z; acc.w += y0.w;
        acc.x += y1.x; acc.y += y1.y; acc.z += y1.z; acc.w += y1.w;
        acc.x += y2.x; acc.y += y2.y; acc.z += y2.z; acc.w += y2.w;
        acc.x += y3.x; acc.y += y3.y; acc.z += y3.z; acc.w += y3.w;
    }
    for (; i < i1; ++i) {
        int e = node_e[i];
        float4 y = *(const float4*)(Y + (size_t)e * 256 + lane * 4);
        acc.x += y.x; acc.y += y.y; acc.z += y.z; acc.w += y.w;
    }
    float inv = (i1 > i0) ? 1.0f / (float)(i1 - i0) : 0.f;
    size_t base = (size_t)v * 256 + lane * 4;
    float4 xi = *(const float4*)(Xinit + base);
    float o[4], mm;
    mm = acc.x * inv; o[0] = (mm > 0.f ? mm : expm1f(mm)) + xi.x;
    mm = acc.y * inv; o[1] = (mm > 0.f ? mm : expm1f(mm)) + xi.y;
    mm = acc.z * inv; o[2] = (mm > 0.f ? mm : expm1f(mm)) + xi.z;
    mm = acc.w * inv; o[3] = (mm > 0.f ? mm : expm1f(mm)) + xi.w;
    u16x4 h, l;
    h.x = f2bf(o[0]); l.x = f2bf(o[0] - bf2f(h.x));
    h.y = f2bf(o[1]); l.y = f2bf(o[1] - bf2f(h.y));
    h.z = f2bf(o[2]); l.z = f2bf(o[2] - bf2f(h.z));
    h.w = f2bf(o[3]); l.w = f2bf(o[3] - bf2f(h.w));
    *(u16x4*)(Hhi + base) = h;
    *(u16x4*)(Hlo + base) = l;
}

// =============== hyperconv ===============
__global__ void deinv_kernel(const int* __restrict__ eoff, const int* __restrict__ edge_v,
                             const int* __restrict__ noff, float* __restrict__ Deinv, int M)
{
    int e = blockIdx.x * blockDim.x + threadIdx.x;
    if (e >= M) return;
    int j0 = eoff[e], j1 = eoff[e + 1];
    float s = 0.f;
    for (int j = j0; j < j1; ++j) {
        int v = edge_v[j];
        s += (float)(noff[v + 1] - noff[v]);
    }
    float De = s / ((float)(j1 - j0) + 1.0f);
    Deinv[e] = De > 0.f ? rsqrtf(De) : 1.0f;
}

__global__ void yh_kernel(const float* __restrict__ Xc,
                          const int* __restrict__ eoff, const int* __restrict__ edge_v,
                          const float* __restrict__ Deinv, float* __restrict__ Yh, int M)
{
    int e = blockIdx.x * 4 + (threadIdx.x >> 6);
    if (e >= M) return;
    int lane = threadIdx.x & 63;
    int j0 = eoff[e], j1 = eoff[e + 1];
    float2 acc = make_float2(0.f, 0.f);
    int j = j0;
    for (; j + 3 < j1; j += 4) {
        int v0 = edge_v[j + 0], v1 = edge_v[j + 1], v2 = edge_v[j + 2], v3 = edge_v[j + 3];
        float2 x0 = *(const float2*)(Xc + (size_t)v0 * 128 + lane * 2);
        float2 x1 = *(const float2*)(Xc + (size_t)v1 * 128 + lane * 2);
        float2 x2 = *(const float2*)(Xc + (size_t)v2 * 128 + lane * 2);
        float2 x3 = *(const float2*)(Xc + (size_t)v3 * 128 + lane * 2);
        acc.x += x0.x + x1.x + x2.x + x3.x;
        acc.y += x0.y + x1.y + x2.y + x3.y;
    }
    for (; j < j1; ++j) {
        int v = edge_v[j];
        float2 x = *(const float2*)(Xc + (size_t)v * 128 + lane * 2);
        acc.x += x.x; acc.y += x.y;
    }
    float sc = ((j1 > j0) ? 1.0f / (float)(j1 - j0) : 0.f) * Deinv[e];
    float* d = Yh + (size_t)e * 128 + lane * 2;
    d[0] = acc.x * sc;
    d[1] = acc.y * sc;
}

__global__ void xo_final_kernel(const float* __restrict__ Yh,
                                const int* __restrict__ noff, const int* __restrict__ node_e,
                                float* __restrict__ out, int N)
{
    int v = blockIdx.x * 4 + (threadIdx.x >> 6);
    if (v >= N) return;
    int lane = threadIdx.x & 63;
    int i0 = noff[v], i1 = noff[v + 1];
    float2 acc = make_float2(0.f, 0.f);
    int i = i0;
    for (; i + 3 < i1; i += 4) {
        int e0 = node_e[i + 0], e1 = node_e[i + 1], e2 = node_e[i + 2], e3 = node_e[i + 3];
        float2 y0 = *(const float2*)(Yh + (size_t)e0 * 128 + lane * 2);
        float2 y1 = *(const float2*)(Yh + (size_t)e1 * 128 + lane * 2);
        float2 y2 = *(const float2*)(Yh + (size_t)e2 * 128 + lane * 2);
        float2 y3 = *(const float2*)(Yh + (size_t)e3 * 128 + lane * 2);
        acc.x += y0.x + y1.x + y2.x + y3.x;
        acc.y += y0.y + y1.y + y2.y + y3.y;
    }
    for (; i < i1; ++i) {
        int e = node_e[i];
        float2 y = *(const float2*)(Yh + (size_t)e * 128 + lane * 2);
        acc.x += y.x; acc.y += y.y;
    }
    float sc = (i1 > i0) ? rsqrtf((float)(i1 - i0)) : 0.f;
    float* d = out + (size_t)v * 128 + lane * 2;
    d[0] = acc.x * sc;
    d[1] = acc.y * sc;
}

// =============== host-side ===============
static void gemm(const u16* Ahi, const u16* Alo, int lda,
                 const u16* Bhi, const u16* Blo, int ldb,
                 const float* bias, float* C, int M, int Nc, int K,
                 hipStream_t stream)
{
    dim3 g((M + 127) / 128, Nc / 128);
    gemm_mfma_kernel<<<g, 256, 0, stream>>>(Ahi, Alo, lda, Bhi, Blo, ldb, bias, C, M, Nc, K);
}

static void run_layer(u16* Ahi, u16* Alo, int K,
                      const u16* WxThi, const u16* WxTlo, const float* bx,
                      const u16* WvThi, const u16* WvTlo, const float* bv,
                      const float* a,
                      const u16* WtThi, const u16* WtTlo, const float* bt,
                      u16* Aehi, u16* Aelo,
                      float* Xinit, float* Xfeat, float* Ybuf, float* score,
                      const int* eoff, const int* edge_v,
                      const int* noff, const int* node_e,
                      int N, int M, hipStream_t stream)
{
    gemm(Ahi, Alo, K, WxThi, WxTlo, K, bx, Xinit, N, 256, K, stream);
    gemm(Ahi, Alo, K, WvThi, WvTlo, K, bv, Xfeat, N, 256, K, stream);
    score_kernel<<<(N + 3) / 4, 256, 0, stream>>>(Xfeat, a, score, N);
    v2e_fused_kernel<<<(M + 3) / 4, 256, 0, stream>>>(Xfeat, score, eoff, edge_v, Aehi, Aelo, M);
    gemm(Aehi, Aelo, 320, WtThi, WtTlo, 320, bt, Ybuf, M, 256, 320, stream);
    e2v_finish_kernel<<<(N + 3) / 4, 256, 0, stream>>>(Ybuf, noff, node_e, Xinit, Ahi, Alo, N);
}

extern "C" void kernel_launch(void* const* d_in, const int* in_sizes, int n_in,
                              void* d_out, int out_size, void* d_ws, size_t ws_size,
                              hipStream_t stream)
{
    const float* X   = (const float*)d_in[0];
    const int*   V   = (const int*)d_in[1];
    const int*   E   = (const int*)d_in[2];
    const float* S   = (const float*)d_in[3];
    const float* Wx0 = (const float*)d_in[4];  const float* bx0 = (const float*)d_in[5];
    const float* Wv0 = (const float*)d_in[6];  const float* bv0 = (const float*)d_in[7];
    const float* a0  = (const float*)d_in[8];
    const float* Wt0 = (const float*)d_in[9];  const float* bt0 = (const float*)d_in[10];
    const float* Wx1 = (const float*)d_in[11]; const float* bx1 = (const float*)d_in[12];
    const float* Wv1 = (const float*)d_in[13]; const float* bv1 = (const float*)d_in[14];
    const float* a1  = (const float*)d_in[15];
    const float* Wt1 = (const float*)d_in[16]; const float* bt1 = (const float*)d_in[17];
    const float* Wf  = (const float*)d_in[18]; const float* bf  = (const float*)d_in[19];

    int N   = in_sizes[0] / 128;
    int NNZ = in_sizes[1];
    int M   = in_sizes[3] / 64;

    float* ws = (float*)d_ws;
    size_t off = 0;
    float* Xinit = ws + off; off += (size_t)N * 256;   // also Yh [M,128] in hyperconv
    float* Xfeat = ws + off; off += (size_t)N * 256;   // also Ybuf [M,256]; also Xc [N,128]
    float* Ybuf  = Xfeat;
    u16* Ahi  = (u16*)(ws + off); off += (size_t)N * 128;  // N*256 u16
    u16* Alo  = (u16*)(ws + off); off += (size_t)N * 128;
    u16* Aehi = (u16*)(ws + off); off += (size_t)M * 160;  // M*320 u16
    u16* Aelo = (u16*)(ws + off); off += (size_t)M * 160;
    u16* WxT0h = (u16*)(ws + off); off += (size_t)(256 * 128) / 2;
    u16* WxT0l = (u16*)(ws + off); off += (size_t)(256 * 128) / 2;
    u16* WvT0h = (u16*)(ws + off); off += (size_t)(256 * 128) / 2;
    u16* WvT0l = (u16*)(ws + off); off += (size_t)(256 * 128) / 2;
    u16* WtT0h = (u16*)(ws + off); off += (size_t)(256 * 320) / 2;
    u16* WtT0l = (u16*)(ws + off); off += (size_t)(256 * 320) / 2;
    u16* WxT1h = (u16*)(ws + off); off += (size_t)(256 * 256) / 2;
    u16* WxT1l = (u16*)(ws + off); off += (size_t)(256 * 256) / 2;
    u16* WvT1h = (u16*)(ws + off); off += (size_t)(256 * 256) / 2;
    u16* WvT1l = (u16*)(ws + off); off += (size_t)(256 * 256) / 2;
    u16* WtT1h = (u16*)(ws + off); off += (size_t)(256 * 320) / 2;
    u16* WtT1l = (u16*)(ws + off); off += (size_t)(256 * 320) / 2;
    u16* WfTh  = (u16*)(ws + off); off += (size_t)(128 * 256) / 2;
    u16* WfTl  = (u16*)(ws + off); off += (size_t)(128 * 256) / 2;
    float* score = ws + off; off += (size_t)N;
    float* Deinv = ws + off; off += (size_t)M;
    int* eoff   = (int*)(ws + off); off += (size_t)(M + 1);
    int* ecnt   = (int*)(ws + off); off += (size_t)M;
    int* ecur   = (int*)(ws + off); off += (size_t)M;
    int* psumE  = (int*)(ws + off); off += 64;
    int* edge_v = (int*)(ws + off); off += (size_t)NNZ;
    int* noff   = (int*)(ws + off); off += (size_t)(N + 1);
    int* ncnt   = (int*)(ws + off); off += (size_t)N;
    int* ncur   = (int*)(ws + off); off += (size_t)N;
    int* psumN  = (int*)(ws + off); off += 64;
    int* node_e = (int*)(ws + off); off += (size_t)NNZ;

    // ---- CSR build (parallel scan) ----
    hipMemsetAsync(ecnt, 0, (size_t)M * 4, stream);
    hipMemsetAsync(ncnt, 0, (size_t)N * 4, stream);
    count_kernel<<<(NNZ + 255) / 256, 256, 0, stream>>>(V, E, ecnt, ncnt, NNZ);
    int nbE = (M + 1023) / 1024, nbN = (N + 1023) / 1024;
    scan_part1<<<nbE, 256, 0, stream>>>(ecnt, eoff, psumE, M);
    scan_part1<<<nbN, 256, 0, stream>>>(ncnt, noff, psumN, N);
    scan_part2<<<nbE, 256, 0, stream>>>(ecnt, eoff, psumE, ecur, M);
    scan_part2<<<nbN, 256, 0, stream>>>(ncnt, noff, psumN, ncur, N);
    fill_kernel<<<(NNZ + 255) / 256, 256, 0, stream>>>(V, E, ecur, ncur, edge_v, node_e, NNZ);

    // ---- input splits ----
    split4_kernel<<<((N * 128 / 4) + 255) / 256, 256, 0, stream>>>(X, Ahi, Alo, N * 128 / 4);
    s_split_kernel<<<((M * 64) + 255) / 256, 256, 0, stream>>>(S, Aehi, Aelo, M);

    // ---- weight transpose+split ----
    wsplitT_kernel<<<(128 * 256 + 255) / 256, 256, 0, stream>>>(Wx0, WxT0h, WxT0l, 128, 8);
    wsplitT_kernel<<<(128 * 256 + 255) / 256, 256, 0, stream>>>(Wv0, WvT0h, WvT0l, 128, 8);
    wsplitT_kernel<<<(320 * 256 + 255) / 256, 256, 0, stream>>>(Wt0, WtT0h, WtT0l, 320, 8);
    wsplitT_kernel<<<(256 * 256 + 255) / 256, 256, 0, stream>>>(Wx1, WxT1h, WxT1l, 256, 8);
    wsplitT_kernel<<<(256 * 256 + 255) / 256, 256, 0, stream>>>(Wv1, WvT1h, WvT1l, 256, 8);
    wsplitT_kernel<<<(320 * 256 + 255) / 256, 256, 0, stream>>>(Wt1, WtT1h, WtT1l, 320, 8);
    wsplitT_kernel<<<(256 * 128 + 255) / 256, 256, 0, stream>>>(Wf, WfTh, WfTl, 256, 7);

    // ---- layers ----
    run_layer(Ahi, Alo, 128, WxT0h, WxT0l, bx0, WvT0h, WvT0l, bv0, a0,
              WtT0h, WtT0l, bt0, Aehi, Aelo, Xinit, Xfeat, Ybuf, score,
              eoff, edge_v, noff, node_e, N, M, stream);
    run_layer(Ahi, Alo, 256, WxT1h, WxT1l, bx1, WvT1h, WvT1l, bv1, a1,
              WtT1h, WtT1l, bt1, Aehi, Aelo, Xinit, Xfeat, Ybuf, score,
              eoff, edge_v, noff, node_e, N, M, stream);

    // ---- hyperconv ----
    float* Xc = Xfeat;   // [N,128] (Ybuf dead)
    float* Yh = Xinit;   // [M,128] (Xinit dead)
    gemm(Ahi, Alo, 256, WfTh, WfTl, 256, bf, Xc, N, 128, 256, stream);
    deinv_kernel<<<(M + 255) / 256, 256, 0, stream>>>(eoff, edge_v, noff, Deinv, M);
    yh_kernel<<<(M + 3) / 4, 256, 0, stream>>>(Xc, eoff, edge_v, Deinv, Yh, M);
    xo_final_kernel<<<(N + 3) / 4, 256, 0, stream>>>(Yh, noff, node_e, (float*)d_out, N);
}